// Round 1
// baseline (2965.836 us; speedup 1.0000x reference)
//
#include <hip/hip_runtime.h>
#include <hip/hip_bf16.h>
#include <math.h>

// ---------------------------------------------------------------------------
// Problem constants
// ---------------------------------------------------------------------------
#define NNODES 100000
#define NEDGES 400000
#define NB     1024
#define SEQ    1000
#define HID    300

// ---------------------------------------------------------------------------
// Generic FP32 GEMM: C = act(A @ B + bias)
// A: M x K (row stride lda), B: K x N (row stride ldb), C: M x N (row stride ldc)
// 64x64 tile, 256 threads, 4x4 per thread.
// ---------------------------------------------------------------------------
__global__ __launch_bounds__(256) void gemm_kernel(
    const float* __restrict__ A, const float* __restrict__ B,
    const float* __restrict__ bias, float* __restrict__ C,
    int M, int N, int K, int lda, int ldb, int ldc, int relu)
{
    __shared__ float As[16][65];  // [k][m]
    __shared__ float Bs[16][68];  // [k][n]
    int tid = threadIdx.x;
    int tx = tid & 15, ty = tid >> 4;
    int row0 = blockIdx.y * 64;
    int col0 = blockIdx.x * 64;
    float acc[4][4] = {};

    for (int k0 = 0; k0 < K; k0 += 16) {
        // load A tile (64 x 16) -> As[k][m]
        #pragma unroll
        for (int i = 0; i < 4; ++i) {
            int l = tid + 256 * i;        // 0..1023
            int m = l >> 4, kk = l & 15;
            int gm = row0 + m, gk = k0 + kk;
            float v = 0.f;
            if (gm < M && gk < K) v = A[(long)gm * lda + gk];
            As[kk][m] = v;
        }
        // load B tile (16 x 64) -> Bs[k][n]
        #pragma unroll
        for (int i = 0; i < 4; ++i) {
            int l = tid + 256 * i;
            int kk = l >> 6, n = l & 63;
            int gk = k0 + kk, gn = col0 + n;
            float v = 0.f;
            if (gk < K && gn < N) v = B[(long)gk * ldb + gn];
            Bs[kk][n] = v;
        }
        __syncthreads();
        #pragma unroll
        for (int kk = 0; kk < 16; ++kk) {
            float a[4], b[4];
            #pragma unroll
            for (int i = 0; i < 4; ++i) a[i] = As[kk][ty * 4 + i];
            #pragma unroll
            for (int j = 0; j < 4; ++j) b[j] = Bs[kk][tx * 4 + j];
            #pragma unroll
            for (int i = 0; i < 4; ++i)
                #pragma unroll
                for (int j = 0; j < 4; ++j) acc[i][j] += a[i] * b[j];
        }
        __syncthreads();
    }
    #pragma unroll
    for (int i = 0; i < 4; ++i) {
        int r = row0 + ty * 4 + i;
        if (r >= M) continue;
        #pragma unroll
        for (int j = 0; j < 4; ++j) {
            int c = col0 + tx * 4 + j;
            if (c >= N) continue;
            float v = acc[i][j];
            if (bias) v += bias[c];
            if (relu) v = fmaxf(v, 0.f);
            C[(long)r * ldc + c] = v;
        }
    }
}

static void launch_gemm(const float* A, const float* B, const float* bias, float* C,
                        int M, int N, int K, int lda, int ldb, int ldc, int relu,
                        hipStream_t stream)
{
    dim3 grid((N + 63) / 64, (M + 63) / 64);
    gemm_kernel<<<grid, 256, 0, stream>>>(A, B, bias, C, M, N, K, lda, ldb, ldc, relu);
}

// ---------------------------------------------------------------------------
// GCN helpers
// ---------------------------------------------------------------------------
__global__ void deg_kernel(const int* __restrict__ dst, int* __restrict__ deg, int E)
{
    int e = blockIdx.x * 256 + threadIdx.x;
    if (e < E) atomicAdd(&deg[dst[e]], 1);
}

__global__ void dis_kernel(const int* __restrict__ deg, float* __restrict__ dis,
                           float* __restrict__ selfc, int n)
{
    int i = blockIdx.x * 256 + threadIdx.x;
    if (i < n) {
        float d = (float)deg[i] + 1.0f;
        float r = 1.0f / sqrtf(d);
        dis[i] = r;
        selfc[i] = r * r;
    }
}

__global__ void norm_kernel(const int* __restrict__ src, const int* __restrict__ dst,
                            const float* __restrict__ dis, float* __restrict__ norm, int E)
{
    int e = blockIdx.x * 256 + threadIdx.x;
    if (e < E) norm[e] = dis[src[e]] * dis[dst[e]];
}

// out[i][f] = T[i][f] * selfc[i]
__global__ void self_term_kernel(const float* __restrict__ T, const float* __restrict__ selfc,
                                 float* __restrict__ out, int total, int F)
{
    int idx = blockIdx.x * 256 + threadIdx.x;
    if (idx < total) {
        int i = idx / F;
        out[idx] = T[idx] * selfc[i];
    }
}

// out[dst][f] += T[src][f] * norm[e]   (one wave per edge, 64 features/wave)
__global__ __launch_bounds__(256) void edge_agg_kernel(
    const float* __restrict__ T, const int* __restrict__ src, const int* __restrict__ dst,
    const float* __restrict__ norm, float* __restrict__ out, int E, int F)
{
    int wave = threadIdx.x >> 6;
    int lane = threadIdx.x & 63;
    int e = blockIdx.x * 4 + wave;
    if (e >= E) return;
    int f = blockIdx.y * 64 + lane;
    if (f >= F) return;
    int s = src[e], d = dst[e];
    float nv = norm[e];
    atomicAdd(&out[(long)d * F + f], T[(long)s * F + f] * nv);
}

__global__ void bias_relu_kernel(float* __restrict__ out, const float* __restrict__ bias,
                                 int total, int F)
{
    int idx = blockIdx.x * 256 + threadIdx.x;
    if (idx < total) {
        int f = idx % F;
        out[idx] = fmaxf(out[idx] + bias[f], 0.f);
    }
}

// segment max pool (values >= 0 after relu -> uint-ordered atomicMax valid)
__global__ void pool_max_kernel(const float* __restrict__ H, const int* __restrict__ batch,
                                unsigned int* __restrict__ g, int total, int F)
{
    int idx = blockIdx.x * 256 + threadIdx.x;
    if (idx < total) {
        int i = idx / F;
        int f = idx - i * F;
        int b = batch[i];
        atomicMax(&g[b * F + f], __float_as_uint(H[idx]));
    }
}

// ---------------------------------------------------------------------------
// Conv branch (letter-bucketed reformulation)
// ---------------------------------------------------------------------------
// conv_w (32,1000,8) -> cwt[i*256 + o*8 + k]
__global__ void conv_transpose_kernel(const float* __restrict__ w, float* __restrict__ wt)
{
    int idx = blockIdx.x * 256 + threadIdx.x;
    if (idx >= 256000) return;
    int o = idx / 8000;
    int rem = idx - o * 8000;
    int i = rem >> 3, k = rem & 7;
    wt[i * 256 + o * 8 + k] = w[idx];
}

// aggw[b][a][o][k] = sum_{i: target[b,i]==a} conv_w[o,i,k]
__global__ __launch_bounds__(256) void conv_agg_kernel(
    const float* __restrict__ cwt, const int* __restrict__ target, float* __restrict__ aggw)
{
    int b = blockIdx.x, tid = threadIdx.x;
    __shared__ float s[26 * 256];
    for (int i = tid; i < 26 * 256; i += 256) s[i] = 0.f;
    __syncthreads();
    const int* tb = target + b * SEQ;
    for (int i = 0; i < SEQ; ++i) {
        int a = tb[i];
        s[a * 256 + tid] += cwt[i * 256 + tid];
    }
    __syncthreads();
    for (int i = tid; i < 26 * 256; i += 256)
        aggw[(long)b * 6656 + i] = s[i];
}

// c[b,o,t] = sum_{a,k} emb_xt[a][t+k]*aggw[b,a,o,k] + conv_b[o]; xt = c @ fc1xt_w + b
__global__ __launch_bounds__(256) void conv_apply_kernel(
    const float* __restrict__ aggw, const float* __restrict__ emb_xt,
    const float* __restrict__ conv_b, const float* __restrict__ w_fc,
    const float* __restrict__ b_fc, float* __restrict__ xc)
{
    int b = blockIdx.x, tid = threadIdx.x;
    __shared__ float es[26 * 128];
    __shared__ float as_[6656];
    __shared__ float cs[3872];
    __shared__ float xred[256];
    for (int i = tid; i < 26 * 128; i += 256) es[i] = emb_xt[i];
    for (int i = tid; i < 6656; i += 256) as_[i] = aggw[(long)b * 6656 + i];
    __syncthreads();
    for (int idx = tid; idx < 3872; idx += 256) {
        int o = idx / 121;
        int t = idx - o * 121;
        float sum = conv_b[o];
        #pragma unroll
        for (int a = 0; a < 26; ++a) {
            const float* ep = es + a * 128 + t;
            const float* ap = as_ + a * 256 + o * 8;
            #pragma unroll
            for (int k = 0; k < 8; ++k) sum += ep[k] * ap[k];
        }
        cs[idx] = sum;  // layout o*121+t == reshape order
    }
    __syncthreads();
    int j = tid & 127, half = tid >> 7;
    float sum = 0.f;
    for (int m = half * 1936; m < (half + 1) * 1936; ++m)
        sum += cs[m] * w_fc[m * 128 + j];
    xred[tid] = sum;
    __syncthreads();
    if (tid < 128)
        xc[(long)b * 384 + 128 + tid] = xred[tid] + xred[tid + 128] + b_fc[tid];
}

// ---------------------------------------------------------------------------
// FG branch: attention row 0 + LayerNorm
// ---------------------------------------------------------------------------
__global__ __launch_bounds__(256) void attn_ln_kernel(
    const float* __restrict__ Fb, const float* __restrict__ Kf, const float* __restrict__ Vf,
    const float* __restrict__ q0, const float* __restrict__ ln_g, const float* __restrict__ ln_b,
    float* __restrict__ out)
{
    int b = blockIdx.x, tid = threadIdx.x;
    __shared__ float qs[HID];
    __shared__ float sc[13];
    __shared__ float red[256];
    __shared__ float red2[256];
    __shared__ float rowv[HID];
    __shared__ float mean_s, inv_s;

    for (int d = tid; d < HID; d += 256) qs[d] = q0[(long)b * HID + d];
    __syncthreads();
    // scores: 13 keys x 16 partial threads
    if (tid < 208) {
        int k = tid >> 4, sub = tid & 15;
        const float* kr = Kf + ((long)b * 13 + k) * HID;
        float p = 0.f;
        for (int d = sub; d < HID; d += 16) p += qs[d] * kr[d];
        red[tid] = p;
    }
    __syncthreads();
    if (tid < 208 && (tid & 15) == 0) {
        float s = 0.f;
        #pragma unroll
        for (int j = 0; j < 16; ++j) s += red[tid + j];
        sc[tid >> 4] = s * 0.0577350269189626f;  // 1/sqrt(300)
    }
    __syncthreads();
    if (tid == 0) {
        float mx = sc[0];
        for (int k = 1; k < 13; ++k) mx = fmaxf(mx, sc[k]);
        float ssum = 0.f;
        for (int k = 0; k < 13; ++k) { float e = expf(sc[k] - mx); sc[k] = e; ssum += e; }
        float inv = 1.0f / ssum;
        for (int k = 0; k < 13; ++k) sc[k] *= inv;
    }
    __syncthreads();
    for (int d = tid; d < HID; d += 256) {
        float v = Fb[((long)b * 13) * HID + d];
        #pragma unroll
        for (int k = 0; k < 13; ++k) v += sc[k] * Vf[((long)b * 13 + k) * HID + d];
        rowv[d] = v;
    }
    __syncthreads();
    float s1 = 0.f, s2 = 0.f;
    for (int d = tid; d < HID; d += 256) { float v = rowv[d]; s1 += v; s2 += v * v; }
    red[tid] = s1; red2[tid] = s2;
    __syncthreads();
    for (int s = 128; s > 0; s >>= 1) {
        if (tid < s) { red[tid] += red[tid + s]; red2[tid] += red2[tid + s]; }
        __syncthreads();
    }
    if (tid == 0) {
        float mean = red[0] / (float)HID;
        float var = red2[0] / (float)HID - mean * mean;
        mean_s = mean;
        inv_s = 1.0f / sqrtf(var + 1e-5f);
    }
    __syncthreads();
    for (int d = tid; d < HID; d += 256)
        out[(long)b * HID + d] = (rowv[d] - mean_s) * inv_s * ln_g[d] + ln_b[d];
}

// ---------------------------------------------------------------------------
// final: out[b] = X[b,:512] . out_w + out_b
// ---------------------------------------------------------------------------
__global__ __launch_bounds__(256) void final_out_kernel(
    const float* __restrict__ X, const float* __restrict__ w,
    const float* __restrict__ bias, float* __restrict__ out)
{
    int b = blockIdx.x, tid = threadIdx.x;
    __shared__ float red[256];
    float p = X[(long)b * 512 + tid] * w[tid] + X[(long)b * 512 + tid + 256] * w[tid + 256];
    red[tid] = p;
    __syncthreads();
    for (int s = 128; s > 0; s >>= 1) {
        if (tid < s) red[tid] += red[tid + s];
        __syncthreads();
    }
    if (tid == 0) out[b] = red[0] + bias[0];
}

// ---------------------------------------------------------------------------
// Host launcher
// ---------------------------------------------------------------------------
extern "C" void kernel_launch(void* const* d_in, const int* in_sizes, int n_in,
                              void* d_out, int out_size, void* d_ws, size_t ws_size,
                              hipStream_t stream)
{
    const float* x        = (const float*)d_in[0];
    const int*   ei       = (const int*)d_in[1];
    const int*   batch    = (const int*)d_in[2];
    const int*   target   = (const int*)d_in[3];
    const float* embs     = (const float*)d_in[4];
    const float* W1       = (const float*)d_in[5];
    const float* b1       = (const float*)d_in[6];
    const float* W2       = (const float*)d_in[7];
    const float* b2       = (const float*)d_in[8];
    const float* W3       = (const float*)d_in[9];
    const float* b3       = (const float*)d_in[10];
    const float* fc_g1_w  = (const float*)d_in[11];
    const float* fc_g1_b  = (const float*)d_in[12];
    const float* fc_g2_w  = (const float*)d_in[13];
    const float* fc_g2_b  = (const float*)d_in[14];
    const float* emb_xt   = (const float*)d_in[15];
    const float* conv_w   = (const float*)d_in[16];
    const float* conv_b   = (const float*)d_in[17];
    const float* fc1xt_w  = (const float*)d_in[18];
    const float* fc1xt_b  = (const float*)d_in[19];
    const float* fg_lin_w = (const float*)d_in[20];
    const float* fg_lin_b = (const float*)d_in[21];
    const float* Wq       = (const float*)d_in[22];
    const float* Wk       = (const float*)d_in[23];
    const float* Wv       = (const float*)d_in[24];
    const float* ln_g     = (const float*)d_in[25];
    const float* ln_b     = (const float*)d_in[26];
    const float* fg_out_w = (const float*)d_in[27];
    const float* fg_out_b = (const float*)d_in[28];
    const float* fc1_w    = (const float*)d_in[29];
    const float* fc1_b    = (const float*)d_in[30];
    const float* fc2_w    = (const float*)d_in[31];
    const float* fc2_b    = (const float*)d_in[32];
    const float* out_w    = (const float*)d_in[33];
    const float* out_b    = (const float*)d_in[34];

    const int* src = ei;
    const int* dst = ei + NEDGES;

    float* ws   = (float*)d_ws;
    float* bufA = ws;                    // 31,200,000 floats
    float* bufT = bufA + 31200000;       // 31,200,000 floats
    float* aux  = bufT + 31200000;
    int*   deg   = (int*)aux;            // 100000
    float* dis   = aux + 100000;         // 100000
    float* selfc = aux + 200000;         // 100000
    float* norm  = aux + 300000;         // 400000
    float* g     = aux + 700000;         // 319488 (1024x312)
    float* G1    = aux + 1019488;        // 1,048,576 (1024x1024)
    float* xc    = aux + 2068064;        // 393,216 (1024x384)
    float* F2    = aux + 2461280;        // 524,288 (1024x512)
    // aliases carved from bufT (free after GCN):
    float* cwt   = bufT;                 // 256,000
    float* aggw  = bufT + 256000;        // 6,815,744
    float* Fbuf  = bufT + 7071744;       // 3,993,600 (13312x300)
    float* Kbuf  = bufT + 11065344;      // 3,993,600
    float* Vbuf  = bufT + 15058944;      // 3,993,600
    float* Qbuf  = bufT + 19052544;      // 307,200 (1024x300)
    float* f2row = bufT + 19359744;      // 307,200

    // ---- degree / norms ----
    hipMemsetAsync(deg, 0, NNODES * sizeof(int), stream);
    deg_kernel<<<(NEDGES + 255) / 256, 256, 0, stream>>>(dst, deg, NEDGES);
    dis_kernel<<<(NNODES + 255) / 256, 256, 0, stream>>>(deg, dis, selfc, NNODES);
    norm_kernel<<<(NEDGES + 255) / 256, 256, 0, stream>>>(src, dst, dis, norm, NEDGES);

    // ---- GCN layer 1 (78 -> 78) ----
    launch_gemm(x, W1, nullptr, bufT, NNODES, 78, 78, 78, 78, 78, 0, stream);
    {
        int F = 78, total = NNODES * F;
        self_term_kernel<<<(total + 255) / 256, 256, 0, stream>>>(bufT, selfc, bufA, total, F);
        edge_agg_kernel<<<dim3(NEDGES / 4, (F + 63) / 64), 256, 0, stream>>>(bufT, src, dst, norm, bufA, NEDGES, F);
        bias_relu_kernel<<<(total + 255) / 256, 256, 0, stream>>>(bufA, b1, total, F);
    }
    // ---- GCN layer 2 (78 -> 156) ----
    launch_gemm(bufA, W2, nullptr, bufT, NNODES, 156, 78, 78, 156, 156, 0, stream);
    {
        int F = 156, total = NNODES * F;
        self_term_kernel<<<(total + 255) / 256, 256, 0, stream>>>(bufT, selfc, bufA, total, F);
        edge_agg_kernel<<<dim3(NEDGES / 4, (F + 63) / 64), 256, 0, stream>>>(bufT, src, dst, norm, bufA, NEDGES, F);
        bias_relu_kernel<<<(total + 255) / 256, 256, 0, stream>>>(bufA, b2, total, F);
    }
    // ---- GCN layer 3 (156 -> 312) ----
    launch_gemm(bufA, W3, nullptr, bufT, NNODES, 312, 156, 156, 312, 312, 0, stream);
    {
        int F = 312, total = NNODES * F;
        self_term_kernel<<<(total + 255) / 256, 256, 0, stream>>>(bufT, selfc, bufA, total, F);
        edge_agg_kernel<<<dim3(NEDGES / 4, (F + 63) / 64), 256, 0, stream>>>(bufT, src, dst, norm, bufA, NEDGES, F);
        bias_relu_kernel<<<(total + 255) / 256, 256, 0, stream>>>(bufA, b3, total, F);
    }

    // ---- global max pool + graph MLP ----
    hipMemsetAsync(g, 0, NB * 312 * sizeof(float), stream);
    pool_max_kernel<<<(NNODES * 312 + 255) / 256, 256, 0, stream>>>(bufA, batch, (unsigned int*)g, NNODES * 312, 312);
    launch_gemm(g, fc_g1_w, fc_g1_b, G1, NB, 1024, 312, 312, 1024, 1024, 1, stream);
    launch_gemm(G1, fc_g2_w, fc_g2_b, xc, NB, 128, 1024, 1024, 128, 384, 0, stream);

    // ---- conv branch ----
    conv_transpose_kernel<<<(256000 + 255) / 256, 256, 0, stream>>>(conv_w, cwt);
    conv_agg_kernel<<<NB, 256, 0, stream>>>(cwt, target, aggw);
    conv_apply_kernel<<<NB, 256, 0, stream>>>(aggw, emb_xt, conv_b, fc1xt_w, fc1xt_b, xc);

    // ---- FG branch ----
    launch_gemm(embs, fg_lin_w, fg_lin_b, Fbuf, NB * 13, HID, 133, 133, HID, HID, 0, stream);
    launch_gemm(Fbuf, Wk, nullptr, Kbuf, NB * 13, HID, HID, HID, HID, HID, 0, stream);
    launch_gemm(Fbuf, Wv, nullptr, Vbuf, NB * 13, HID, HID, HID, HID, HID, 0, stream);
    launch_gemm(Fbuf, Wq, nullptr, Qbuf, NB, HID, HID, 13 * HID, HID, HID, 0, stream);  // rows b*13
    attn_ln_kernel<<<NB, 256, 0, stream>>>(Fbuf, Kbuf, Vbuf, Qbuf, ln_g, ln_b, f2row);
    launch_gemm(f2row, fg_out_w, fg_out_b, xc + 256, NB, 128, HID, HID, 128, 384, 0, stream);

    // ---- head ----
    launch_gemm(xc, fc1_w, fc1_b, G1, NB, 1024, 384, 384, 1024, 1024, 1, stream);
    launch_gemm(G1, fc2_w, fc2_b, F2, NB, 512, 1024, 1024, 512, 512, 1, stream);
    final_out_kernel<<<NB, 256, 0, stream>>>(F2, out_w, out_b, (float*)d_out);
}

// Round 2
// 2543.510 us; speedup vs baseline: 1.1660x; 1.1660x over previous
//
#include <hip/hip_runtime.h>
#include <hip/hip_bf16.h>
#include <math.h>

// ---------------------------------------------------------------------------
// Problem constants
// ---------------------------------------------------------------------------
#define NNODES 100000
#define NEDGES 400000
#define NB     1024
#define SEQ    1000
#define HID    300

// ---------------------------------------------------------------------------
// Generic FP32 GEMM: C = act(A @ B + bias)
// ---------------------------------------------------------------------------
__global__ __launch_bounds__(256) void gemm_kernel(
    const float* __restrict__ A, const float* __restrict__ B,
    const float* __restrict__ bias, float* __restrict__ C,
    int M, int N, int K, int lda, int ldb, int ldc, int relu)
{
    __shared__ float As[16][65];  // [k][m]
    __shared__ float Bs[16][68];  // [k][n]
    int tid = threadIdx.x;
    int tx = tid & 15, ty = tid >> 4;
    int row0 = blockIdx.y * 64;
    int col0 = blockIdx.x * 64;
    float acc[4][4] = {};

    for (int k0 = 0; k0 < K; k0 += 16) {
        #pragma unroll
        for (int i = 0; i < 4; ++i) {
            int l = tid + 256 * i;
            int m = l >> 4, kk = l & 15;
            int gm = row0 + m, gk = k0 + kk;
            float v = 0.f;
            if (gm < M && gk < K) v = A[(long)gm * lda + gk];
            As[kk][m] = v;
        }
        #pragma unroll
        for (int i = 0; i < 4; ++i) {
            int l = tid + 256 * i;
            int kk = l >> 6, n = l & 63;
            int gk = k0 + kk, gn = col0 + n;
            float v = 0.f;
            if (gk < K && gn < N) v = B[(long)gk * ldb + gn];
            Bs[kk][n] = v;
        }
        __syncthreads();
        #pragma unroll
        for (int kk = 0; kk < 16; ++kk) {
            float a[4], b[4];
            #pragma unroll
            for (int i = 0; i < 4; ++i) a[i] = As[kk][ty * 4 + i];
            #pragma unroll
            for (int j = 0; j < 4; ++j) b[j] = Bs[kk][tx * 4 + j];
            #pragma unroll
            for (int i = 0; i < 4; ++i)
                #pragma unroll
                for (int j = 0; j < 4; ++j) acc[i][j] += a[i] * b[j];
        }
        __syncthreads();
    }
    #pragma unroll
    for (int i = 0; i < 4; ++i) {
        int r = row0 + ty * 4 + i;
        if (r >= M) continue;
        #pragma unroll
        for (int j = 0; j < 4; ++j) {
            int c = col0 + tx * 4 + j;
            if (c >= N) continue;
            float v = acc[i][j];
            if (bias) v += bias[c];
            if (relu) v = fmaxf(v, 0.f);
            C[(long)r * ldc + c] = v;
        }
    }
}

static void launch_gemm(const float* A, const float* B, const float* bias, float* C,
                        int M, int N, int K, int lda, int ldb, int ldc, int relu,
                        hipStream_t stream)
{
    dim3 grid((N + 63) / 64, (M + 63) / 64);
    gemm_kernel<<<grid, 256, 0, stream>>>(A, B, bias, C, M, N, K, lda, ldb, ldc, relu);
}

// ---------------------------------------------------------------------------
// GCN: degree, norms, CSR build
// ---------------------------------------------------------------------------
__global__ void deg_kernel(const int* __restrict__ dst, int* __restrict__ deg, int E)
{
    int e = blockIdx.x * 256 + threadIdx.x;
    if (e < E) atomicAdd(&deg[dst[e]], 1);
}

__global__ void dis_kernel(const int* __restrict__ deg, float* __restrict__ dis,
                           float* __restrict__ selfc, int n)
{
    int i = blockIdx.x * 256 + threadIdx.x;
    if (i < n) {
        float d = (float)deg[i] + 1.0f;
        float r = 1.0f / sqrtf(d);
        dis[i] = r;
        selfc[i] = r * r;
    }
}

// exclusive scan of deg[0..NNODES) into off, single block of 1024 threads
__global__ __launch_bounds__(1024) void scan_kernel(const int* __restrict__ deg,
                                                    int* __restrict__ off)
{
    __shared__ int ssum[1024];
    int tid = threadIdx.x;
    const int CH = (NNODES + 1023) / 1024;  // 98
    int start = tid * CH;
    int end = start + CH; if (end > NNODES) end = NNODES;
    int s = 0;
    for (int i = start; i < end && i < NNODES; ++i) s += deg[i];
    ssum[tid] = s;
    __syncthreads();
    // Hillis-Steele inclusive scan
    for (int d = 1; d < 1024; d <<= 1) {
        int v = ssum[tid];
        int add = (tid >= d) ? ssum[tid - d] : 0;
        __syncthreads();
        ssum[tid] = v + add;
        __syncthreads();
    }
    int pre = ssum[tid] - s;  // exclusive prefix
    for (int i = start; i < end && i < NNODES; ++i) { off[i] = pre; pre += deg[i]; }
    if (tid == 0) off[NNODES] = NEDGES;
}

// cur[i] = off[i]  (cur aliases the deg buffer)
__global__ void cur_init_kernel(const int* __restrict__ off, int* __restrict__ cur, int n)
{
    int i = blockIdx.x * 256 + threadIdx.x;
    if (i < n) cur[i] = off[i];
}

__global__ void fill_csr_kernel(const int* __restrict__ src, const int* __restrict__ dst,
                                const float* __restrict__ dis, int* __restrict__ cur,
                                int* __restrict__ csr_src, float* __restrict__ csr_w, int E)
{
    int e = blockIdx.x * 256 + threadIdx.x;
    if (e >= E) return;
    int s = src[e], d = dst[e];
    int p = atomicAdd(&cur[d], 1);
    csr_src[p] = s;
    csr_w[p] = dis[s] * dis[d];
}

// ---------------------------------------------------------------------------
// Fused GCN aggregation: out[i,f] = relu(bias[f] + selfc[i]*T[i,f] + sum_e w*T[src,f])
// one wave per (4-node block row, 64-feature block column)
// ---------------------------------------------------------------------------
__global__ __launch_bounds__(256) void gcn_agg_fused(
    const float* __restrict__ T, const int* __restrict__ off,
    const int* __restrict__ csr_src, const float* __restrict__ csr_w,
    const float* __restrict__ selfc, const float* __restrict__ bias,
    float* __restrict__ out, int F)
{
    int wave = threadIdx.x >> 6;
    int lane = threadIdx.x & 63;
    int node = blockIdx.x * 4 + wave;
    if (node >= NNODES) return;
    int f = blockIdx.y * 64 + lane;
    if (f >= F) return;
    int s0 = off[node], s1 = off[node + 1];
    float acc = T[(long)node * F + f] * selfc[node];
    for (int e = s0; e < s1; ++e) {
        int s = csr_src[e];
        acc += T[(long)s * F + f] * csr_w[e];
    }
    out[(long)node * F + f] = fmaxf(acc + bias[f], 0.f);
}

// ---------------------------------------------------------------------------
// segment max pool: one block per molecule, batch is sorted
// ---------------------------------------------------------------------------
__global__ __launch_bounds__(256) void pool_max_kernel(
    const float* __restrict__ H, const int* __restrict__ batch, float* __restrict__ g)
{
    int b = blockIdx.x;
    int lo = 0, hi = NNODES;
    while (lo < hi) { int mid = (lo + hi) >> 1; if (batch[mid] < b) lo = mid + 1; else hi = mid; }
    int s = lo;
    hi = NNODES;
    while (lo < hi) { int mid = (lo + hi) >> 1; if (batch[mid] < b + 1) lo = mid + 1; else hi = mid; }
    int e = lo;
    for (int f = threadIdx.x; f < 312; f += 256) {
        float m = 0.f;  // empty segment -> 0 (matches isfinite-replacement); values >= 0 post-relu
        for (int i = s; i < e; ++i) m = fmaxf(m, H[(long)i * 312 + f]);
        g[(long)b * 312 + f] = m;
    }
}

// ---------------------------------------------------------------------------
// Conv branch (letter-bucketed reformulation)
// ---------------------------------------------------------------------------
__global__ void conv_transpose_kernel(const float* __restrict__ w, float* __restrict__ wt)
{
    int idx = blockIdx.x * 256 + threadIdx.x;
    if (idx >= 256000) return;
    int o = idx / 8000;
    int rem = idx - o * 8000;
    int i = rem >> 3, k = rem & 7;
    wt[i * 256 + o * 8 + k] = w[idx];
}

__global__ __launch_bounds__(256) void conv_agg_kernel(
    const float* __restrict__ cwt, const int* __restrict__ target, float* __restrict__ aggw)
{
    int b = blockIdx.x, tid = threadIdx.x;
    __shared__ float s[26 * 256];
    for (int i = tid; i < 26 * 256; i += 256) s[i] = 0.f;
    __syncthreads();
    const int* tb = target + b * SEQ;
    for (int i = 0; i < SEQ; ++i) {
        int a = tb[i];
        s[a * 256 + tid] += cwt[i * 256 + tid];
    }
    __syncthreads();
    for (int i = tid; i < 26 * 256; i += 256)
        aggw[(long)b * 6656 + i] = s[i];
}

__global__ __launch_bounds__(256) void conv_apply_kernel(
    const float* __restrict__ aggw, const float* __restrict__ emb_xt,
    const float* __restrict__ conv_b, const float* __restrict__ w_fc,
    const float* __restrict__ b_fc, float* __restrict__ xc)
{
    int b = blockIdx.x, tid = threadIdx.x;
    __shared__ float es[26 * 128];
    __shared__ float as_[6656];
    __shared__ float cs[3872];
    __shared__ float xred[256];
    for (int i = tid; i < 26 * 128; i += 256) es[i] = emb_xt[i];
    for (int i = tid; i < 6656; i += 256) as_[i] = aggw[(long)b * 6656 + i];
    __syncthreads();
    for (int idx = tid; idx < 3872; idx += 256) {
        int o = idx / 121;
        int t = idx - o * 121;
        float sum = conv_b[o];
        #pragma unroll
        for (int a = 0; a < 26; ++a) {
            const float* ep = es + a * 128 + t;
            const float* ap = as_ + a * 256 + o * 8;
            #pragma unroll
            for (int k = 0; k < 8; ++k) sum += ep[k] * ap[k];
        }
        cs[idx] = sum;
    }
    __syncthreads();
    int j = tid & 127, half = tid >> 7;
    float sum = 0.f;
    for (int m = half * 1936; m < (half + 1) * 1936; ++m)
        sum += cs[m] * w_fc[m * 128 + j];
    xred[tid] = sum;
    __syncthreads();
    if (tid < 128)
        xc[(long)b * 384 + 128 + tid] = xred[tid] + xred[tid + 128] + b_fc[tid];
}

// ---------------------------------------------------------------------------
// FG branch: attention row 0 + LayerNorm
// ---------------------------------------------------------------------------
__global__ __launch_bounds__(256) void attn_ln_kernel(
    const float* __restrict__ Fb, const float* __restrict__ Kf, const float* __restrict__ Vf,
    const float* __restrict__ q0, const float* __restrict__ ln_g, const float* __restrict__ ln_b,
    float* __restrict__ out)
{
    int b = blockIdx.x, tid = threadIdx.x;
    __shared__ float qs[HID];
    __shared__ float sc[13];
    __shared__ float red[256];
    __shared__ float red2[256];
    __shared__ float rowv[HID];
    __shared__ float mean_s, inv_s;

    for (int d = tid; d < HID; d += 256) qs[d] = q0[(long)b * HID + d];
    __syncthreads();
    if (tid < 208) {
        int k = tid >> 4, sub = tid & 15;
        const float* kr = Kf + ((long)b * 13 + k) * HID;
        float p = 0.f;
        for (int d = sub; d < HID; d += 16) p += qs[d] * kr[d];
        red[tid] = p;
    }
    __syncthreads();
    if (tid < 208 && (tid & 15) == 0) {
        float s = 0.f;
        #pragma unroll
        for (int j = 0; j < 16; ++j) s += red[tid + j];
        sc[tid >> 4] = s * 0.0577350269189626f;  // 1/sqrt(300)
    }
    __syncthreads();
    if (tid == 0) {
        float mx = sc[0];
        for (int k = 1; k < 13; ++k) mx = fmaxf(mx, sc[k]);
        float ssum = 0.f;
        for (int k = 0; k < 13; ++k) { float e = expf(sc[k] - mx); sc[k] = e; ssum += e; }
        float inv = 1.0f / ssum;
        for (int k = 0; k < 13; ++k) sc[k] *= inv;
    }
    __syncthreads();
    for (int d = tid; d < HID; d += 256) {
        float v = Fb[((long)b * 13) * HID + d];
        #pragma unroll
        for (int k = 0; k < 13; ++k) v += sc[k] * Vf[((long)b * 13 + k) * HID + d];
        rowv[d] = v;
    }
    __syncthreads();
    float s1 = 0.f, s2 = 0.f;
    for (int d = tid; d < HID; d += 256) { float v = rowv[d]; s1 += v; s2 += v * v; }
    red[tid] = s1; red2[tid] = s2;
    __syncthreads();
    for (int s = 128; s > 0; s >>= 1) {
        if (tid < s) { red[tid] += red[tid + s]; red2[tid] += red2[tid + s]; }
        __syncthreads();
    }
    if (tid == 0) {
        float mean = red[0] / (float)HID;
        float var = red2[0] / (float)HID - mean * mean;
        mean_s = mean;
        inv_s = 1.0f / sqrtf(var + 1e-5f);
    }
    __syncthreads();
    for (int d = tid; d < HID; d += 256)
        out[(long)b * HID + d] = (rowv[d] - mean_s) * inv_s * ln_g[d] + ln_b[d];
}

// ---------------------------------------------------------------------------
// final: out[b] = X[b,:512] . out_w + out_b
// ---------------------------------------------------------------------------
__global__ __launch_bounds__(256) void final_out_kernel(
    const float* __restrict__ X, const float* __restrict__ w,
    const float* __restrict__ bias, float* __restrict__ out)
{
    int b = blockIdx.x, tid = threadIdx.x;
    __shared__ float red[256];
    float p = X[(long)b * 512 + tid] * w[tid] + X[(long)b * 512 + tid + 256] * w[tid + 256];
    red[tid] = p;
    __syncthreads();
    for (int s = 128; s > 0; s >>= 1) {
        if (tid < s) red[tid] += red[tid + s];
        __syncthreads();
    }
    if (tid == 0) out[b] = red[0] + bias[0];
}

// ---------------------------------------------------------------------------
// Host launcher
// ---------------------------------------------------------------------------
extern "C" void kernel_launch(void* const* d_in, const int* in_sizes, int n_in,
                              void* d_out, int out_size, void* d_ws, size_t ws_size,
                              hipStream_t stream)
{
    const float* x        = (const float*)d_in[0];
    const int*   ei       = (const int*)d_in[1];
    const int*   batch    = (const int*)d_in[2];
    const int*   target   = (const int*)d_in[3];
    const float* embs     = (const float*)d_in[4];
    const float* W1       = (const float*)d_in[5];
    const float* b1       = (const float*)d_in[6];
    const float* W2       = (const float*)d_in[7];
    const float* b2       = (const float*)d_in[8];
    const float* W3       = (const float*)d_in[9];
    const float* b3       = (const float*)d_in[10];
    const float* fc_g1_w  = (const float*)d_in[11];
    const float* fc_g1_b  = (const float*)d_in[12];
    const float* fc_g2_w  = (const float*)d_in[13];
    const float* fc_g2_b  = (const float*)d_in[14];
    const float* emb_xt   = (const float*)d_in[15];
    const float* conv_w   = (const float*)d_in[16];
    const float* conv_b   = (const float*)d_in[17];
    const float* fc1xt_w  = (const float*)d_in[18];
    const float* fc1xt_b  = (const float*)d_in[19];
    const float* fg_lin_w = (const float*)d_in[20];
    const float* fg_lin_b = (const float*)d_in[21];
    const float* Wq       = (const float*)d_in[22];
    const float* Wk       = (const float*)d_in[23];
    const float* Wv       = (const float*)d_in[24];
    const float* ln_g     = (const float*)d_in[25];
    const float* ln_b     = (const float*)d_in[26];
    const float* fg_out_w = (const float*)d_in[27];
    const float* fg_out_b = (const float*)d_in[28];
    const float* fc1_w    = (const float*)d_in[29];
    const float* fc1_b    = (const float*)d_in[30];
    const float* fc2_w    = (const float*)d_in[31];
    const float* fc2_b    = (const float*)d_in[32];
    const float* out_w    = (const float*)d_in[33];
    const float* out_b    = (const float*)d_in[34];

    const int* src = ei;
    const int* dst = ei + NEDGES;

    float* ws   = (float*)d_ws;
    float* bufA = ws;                    // 31,200,000 floats
    float* bufT = bufA + 31200000;       // 31,200,000 floats
    float* aux  = bufT + 31200000;
    int*   deg     = (int*)aux;          // 100000 (reused as CSR cursor)
    float* dis     = aux + 100000;       // 100000
    float* selfc   = aux + 200000;       // 100000
    int*   off     = (int*)(aux + 300000);   // 100004
    int*   csr_src = (int*)(aux + 400004);   // 400000
    float* csr_w   = aux + 800004;       // 400000
    float* g       = aux + 1200004;      // 319488 (1024x312)
    float* G1      = aux + 1519492;      // 1,048,576 (1024x1024)
    float* xc      = aux + 2568068;      // 393,216 (1024x384)
    float* F2      = aux + 2961284;      // 524,288 (1024x512)
    // aliases carved from bufT (free after GCN):
    float* cwt   = bufT;                 // 256,000
    float* aggw  = bufT + 256000;        // 6,815,744
    float* Fbuf  = bufT + 7071744;       // 3,993,600 (13312x300)
    float* Kbuf  = bufT + 11065344;      // 3,993,600
    float* Vbuf  = bufT + 15058944;      // 3,993,600
    float* Qbuf  = bufT + 19052544;      // 307,200 (1024x300)
    float* f2row = bufT + 19359744;      // 307,200

    // ---- degree / norms / CSR ----
    hipMemsetAsync(deg, 0, NNODES * sizeof(int), stream);
    deg_kernel<<<(NEDGES + 255) / 256, 256, 0, stream>>>(dst, deg, NEDGES);
    dis_kernel<<<(NNODES + 255) / 256, 256, 0, stream>>>(deg, dis, selfc, NNODES);
    scan_kernel<<<1, 1024, 0, stream>>>(deg, off);
    cur_init_kernel<<<(NNODES + 255) / 256, 256, 0, stream>>>(off, deg, NNODES);
    fill_csr_kernel<<<(NEDGES + 255) / 256, 256, 0, stream>>>(src, dst, dis, deg, csr_src, csr_w, NEDGES);

    // ---- GCN layers: GEMM -> fused gather-agg(+bias+relu) ----
    launch_gemm(x, W1, nullptr, bufT, NNODES, 78, 78, 78, 78, 78, 0, stream);
    gcn_agg_fused<<<dim3((NNODES + 3) / 4, 2), 256, 0, stream>>>(bufT, off, csr_src, csr_w, selfc, b1, bufA, 78);

    launch_gemm(bufA, W2, nullptr, bufT, NNODES, 156, 78, 78, 156, 156, 0, stream);
    gcn_agg_fused<<<dim3((NNODES + 3) / 4, 3), 256, 0, stream>>>(bufT, off, csr_src, csr_w, selfc, b2, bufA, 156);

    launch_gemm(bufA, W3, nullptr, bufT, NNODES, 312, 156, 156, 312, 312, 0, stream);
    gcn_agg_fused<<<dim3((NNODES + 3) / 4, 5), 256, 0, stream>>>(bufT, off, csr_src, csr_w, selfc, b3, bufA, 312);

    // ---- global max pool + graph MLP ----
    pool_max_kernel<<<NB, 256, 0, stream>>>(bufA, batch, g);
    launch_gemm(g, fc_g1_w, fc_g1_b, G1, NB, 1024, 312, 312, 1024, 1024, 1, stream);
    launch_gemm(G1, fc_g2_w, fc_g2_b, xc, NB, 128, 1024, 1024, 128, 384, 0, stream);

    // ---- conv branch ----
    conv_transpose_kernel<<<(256000 + 255) / 256, 256, 0, stream>>>(conv_w, cwt);
    conv_agg_kernel<<<NB, 256, 0, stream>>>(cwt, target, aggw);
    conv_apply_kernel<<<NB, 256, 0, stream>>>(aggw, emb_xt, conv_b, fc1xt_w, fc1xt_b, xc);

    // ---- FG branch ----
    launch_gemm(embs, fg_lin_w, fg_lin_b, Fbuf, NB * 13, HID, 133, 133, HID, HID, 0, stream);
    launch_gemm(Fbuf, Wk, nullptr, Kbuf, NB * 13, HID, HID, HID, HID, HID, 0, stream);
    launch_gemm(Fbuf, Wv, nullptr, Vbuf, NB * 13, HID, HID, HID, HID, HID, 0, stream);
    launch_gemm(Fbuf, Wq, nullptr, Qbuf, NB, HID, HID, 13 * HID, HID, HID, 0, stream);
    attn_ln_kernel<<<NB, 256, 0, stream>>>(Fbuf, Kbuf, Vbuf, Qbuf, ln_g, ln_b, f2row);
    launch_gemm(f2row, fg_out_w, fg_out_b, xc + 256, NB, 128, HID, HID, 128, 384, 0, stream);

    // ---- head ----
    launch_gemm(xc, fc1_w, fc1_b, G1, NB, 1024, 384, 384, 1024, 1024, 1, stream);
    launch_gemm(G1, fc2_w, fc2_b, F2, NB, 512, 1024, 1024, 512, 512, 1, stream);
    final_out_kernel<<<NB, 256, 0, stream>>>(F2, out_w, out_b, (float*)d_out);
}

// Round 3
// 2382.809 us; speedup vs baseline: 1.2447x; 1.0674x over previous
//
#include <hip/hip_runtime.h>
#include <hip/hip_bf16.h>
#include <math.h>

// ---------------------------------------------------------------------------
// Problem constants
// ---------------------------------------------------------------------------
#define NNODES 100000
#define NEDGES 400000
#define NB     1024
#define SEQ    1000
#define HID    300

// ---------------------------------------------------------------------------
// Generic FP32 GEMM: C = act(A @ B + bias)
// ---------------------------------------------------------------------------
__global__ __launch_bounds__(256) void gemm_kernel(
    const float* __restrict__ A, const float* __restrict__ B,
    const float* __restrict__ bias, float* __restrict__ C,
    int M, int N, int K, int lda, int ldb, int ldc, int relu)
{
    __shared__ float As[16][65];  // [k][m]
    __shared__ float Bs[16][68];  // [k][n]
    int tid = threadIdx.x;
    int tx = tid & 15, ty = tid >> 4;
    int row0 = blockIdx.y * 64;
    int col0 = blockIdx.x * 64;
    float acc[4][4] = {};

    for (int k0 = 0; k0 < K; k0 += 16) {
        #pragma unroll
        for (int i = 0; i < 4; ++i) {
            int l = tid + 256 * i;
            int m = l >> 4, kk = l & 15;
            int gm = row0 + m, gk = k0 + kk;
            float v = 0.f;
            if (gm < M && gk < K) v = A[(long)gm * lda + gk];
            As[kk][m] = v;
        }
        #pragma unroll
        for (int i = 0; i < 4; ++i) {
            int l = tid + 256 * i;
            int kk = l >> 6, n = l & 63;
            int gk = k0 + kk, gn = col0 + n;
            float v = 0.f;
            if (gk < K && gn < N) v = B[(long)gk * ldb + gn];
            Bs[kk][n] = v;
        }
        __syncthreads();
        #pragma unroll
        for (int kk = 0; kk < 16; ++kk) {
            float a[4], b[4];
            #pragma unroll
            for (int i = 0; i < 4; ++i) a[i] = As[kk][ty * 4 + i];
            #pragma unroll
            for (int j = 0; j < 4; ++j) b[j] = Bs[kk][tx * 4 + j];
            #pragma unroll
            for (int i = 0; i < 4; ++i)
                #pragma unroll
                for (int j = 0; j < 4; ++j) acc[i][j] += a[i] * b[j];
        }
        __syncthreads();
    }
    #pragma unroll
    for (int i = 0; i < 4; ++i) {
        int r = row0 + ty * 4 + i;
        if (r >= M) continue;
        #pragma unroll
        for (int j = 0; j < 4; ++j) {
            int c = col0 + tx * 4 + j;
            if (c >= N) continue;
            float v = acc[i][j];
            if (bias) v += bias[c];
            if (relu) v = fmaxf(v, 0.f);
            C[(long)r * ldc + c] = v;
        }
    }
}

static void launch_gemm(const float* A, const float* B, const float* bias, float* C,
                        int M, int N, int K, int lda, int ldb, int ldc, int relu,
                        hipStream_t stream)
{
    dim3 grid((N + 63) / 64, (M + 63) / 64);
    gemm_kernel<<<grid, 256, 0, stream>>>(A, B, bias, C, M, N, K, lda, ldb, ldc, relu);
}

// ---------------------------------------------------------------------------
// Split-K GEMM: C += A @ B (C pre-initialized with bias), fp32 atomics
// ---------------------------------------------------------------------------
__global__ __launch_bounds__(256) void gemm_splitk_kernel(
    const float* __restrict__ A, const float* __restrict__ B, float* __restrict__ C,
    int M, int N, int K, int lda, int ldb, int ldc, int kchunk)
{
    __shared__ float As[16][65];
    __shared__ float Bs[16][68];
    int tid = threadIdx.x;
    int tx = tid & 15, ty = tid >> 4;
    int row0 = blockIdx.y * 64;
    int col0 = blockIdx.x * 64;
    int kbeg = blockIdx.z * kchunk;
    int kend = kbeg + kchunk; if (kend > K) kend = K;
    float acc[4][4] = {};

    for (int k0 = kbeg; k0 < kend; k0 += 16) {
        #pragma unroll
        for (int i = 0; i < 4; ++i) {
            int l = tid + 256 * i;
            int m = l >> 4, kk = l & 15;
            int gm = row0 + m, gk = k0 + kk;
            float v = 0.f;
            if (gm < M && gk < K) v = A[(long)gm * lda + gk];
            As[kk][m] = v;
        }
        #pragma unroll
        for (int i = 0; i < 4; ++i) {
            int l = tid + 256 * i;
            int kk = l >> 6, n = l & 63;
            int gk = k0 + kk, gn = col0 + n;
            float v = 0.f;
            if (gk < K && gn < N) v = B[(long)gk * ldb + gn];
            Bs[kk][n] = v;
        }
        __syncthreads();
        #pragma unroll
        for (int kk = 0; kk < 16; ++kk) {
            float a[4], b[4];
            #pragma unroll
            for (int i = 0; i < 4; ++i) a[i] = As[kk][ty * 4 + i];
            #pragma unroll
            for (int j = 0; j < 4; ++j) b[j] = Bs[kk][tx * 4 + j];
            #pragma unroll
            for (int i = 0; i < 4; ++i)
                #pragma unroll
                for (int j = 0; j < 4; ++j) acc[i][j] += a[i] * b[j];
        }
        __syncthreads();
    }
    #pragma unroll
    for (int i = 0; i < 4; ++i) {
        int r = row0 + ty * 4 + i;
        if (r >= M) continue;
        #pragma unroll
        for (int j = 0; j < 4; ++j) {
            int c = col0 + tx * 4 + j;
            if (c >= N) continue;
            atomicAdd(&C[(long)r * ldc + c], acc[i][j]);
        }
    }
}

// ---------------------------------------------------------------------------
// GCN: degree, norms, CSR build
// ---------------------------------------------------------------------------
__global__ void deg_kernel(const int* __restrict__ dst, int* __restrict__ deg, int E)
{
    int e = blockIdx.x * 256 + threadIdx.x;
    if (e < E) atomicAdd(&deg[dst[e]], 1);
}

__global__ void dis_kernel(const int* __restrict__ deg, float* __restrict__ dis,
                           float* __restrict__ selfc, int n)
{
    int i = blockIdx.x * 256 + threadIdx.x;
    if (i < n) {
        float d = (float)deg[i] + 1.0f;
        float r = 1.0f / sqrtf(d);
        dis[i] = r;
        selfc[i] = r * r;
    }
}

__global__ __launch_bounds__(1024) void scan_kernel(const int* __restrict__ deg,
                                                    int* __restrict__ off)
{
    __shared__ int ssum[1024];
    int tid = threadIdx.x;
    const int CH = (NNODES + 1023) / 1024;  // 98
    int start = tid * CH;
    int end = start + CH; if (end > NNODES) end = NNODES;
    int s = 0;
    for (int i = start; i < end && i < NNODES; ++i) s += deg[i];
    ssum[tid] = s;
    __syncthreads();
    for (int d = 1; d < 1024; d <<= 1) {
        int v = ssum[tid];
        int add = (tid >= d) ? ssum[tid - d] : 0;
        __syncthreads();
        ssum[tid] = v + add;
        __syncthreads();
    }
    int pre = ssum[tid] - s;
    for (int i = start; i < end && i < NNODES; ++i) { off[i] = pre; pre += deg[i]; }
    if (tid == 0) off[NNODES] = NEDGES;
}

__global__ void cur_init_kernel(const int* __restrict__ off, int* __restrict__ cur, int n)
{
    int i = blockIdx.x * 256 + threadIdx.x;
    if (i < n) cur[i] = off[i];
}

__global__ void fill_csr_kernel(const int* __restrict__ src, const int* __restrict__ dst,
                                const float* __restrict__ dis, int* __restrict__ cur,
                                int* __restrict__ csr_src, float* __restrict__ csr_w, int E)
{
    int e = blockIdx.x * 256 + threadIdx.x;
    if (e >= E) return;
    int s = src[e], d = dst[e];
    int p = atomicAdd(&cur[d], 1);
    csr_src[p] = s;
    csr_w[p] = dis[s] * dis[d];
}

// ---------------------------------------------------------------------------
// Fused GCN aggregation
// ---------------------------------------------------------------------------
__global__ __launch_bounds__(256) void gcn_agg_fused(
    const float* __restrict__ T, const int* __restrict__ off,
    const int* __restrict__ csr_src, const float* __restrict__ csr_w,
    const float* __restrict__ selfc, const float* __restrict__ bias,
    float* __restrict__ out, int F)
{
    int wave = threadIdx.x >> 6;
    int lane = threadIdx.x & 63;
    int node = blockIdx.x * 4 + wave;
    if (node >= NNODES) return;
    int f = blockIdx.y * 64 + lane;
    if (f >= F) return;
    int s0 = off[node], s1 = off[node + 1];
    float acc = T[(long)node * F + f] * selfc[node];
    for (int e = s0; e < s1; ++e) {
        int s = csr_src[e];
        acc += T[(long)s * F + f] * csr_w[e];
    }
    out[(long)node * F + f] = fmaxf(acc + bias[f], 0.f);
}

// ---------------------------------------------------------------------------
// segment max pool: one block per molecule, batch is sorted
// ---------------------------------------------------------------------------
__global__ __launch_bounds__(256) void pool_max_kernel(
    const float* __restrict__ H, const int* __restrict__ batch, float* __restrict__ g)
{
    int b = blockIdx.x;
    int lo = 0, hi = NNODES;
    while (lo < hi) { int mid = (lo + hi) >> 1; if (batch[mid] < b) lo = mid + 1; else hi = mid; }
    int s = lo;
    hi = NNODES;
    while (lo < hi) { int mid = (lo + hi) >> 1; if (batch[mid] < b + 1) lo = mid + 1; else hi = mid; }
    int e = lo;
    for (int f = threadIdx.x; f < 312; f += 256) {
        float m = 0.f;
        for (int i = s; i < e; ++i) m = fmaxf(m, H[(long)i * 312 + f]);
        g[(long)b * 312 + f] = m;
    }
}

// ---------------------------------------------------------------------------
// Conv branch: bucketing + weight folding
// ---------------------------------------------------------------------------
// conv_w (32,1000,8) -> cwt[i*256 + o*8 + k]
__global__ void conv_transpose_kernel(const float* __restrict__ w, float* __restrict__ wt)
{
    int idx = blockIdx.x * 256 + threadIdx.x;
    if (idx >= 256000) return;
    int o = idx / 8000;
    int rem = idx - o * 8000;
    int i = rem >> 3, k = rem & 7;
    wt[i * 256 + o * 8 + k] = w[idx];
}

// aggw[b][a*256 + o*8 + k] = sum_{i: target[b,i]==a} conv_w[o,i,k]
__global__ __launch_bounds__(256) void conv_agg_kernel(
    const float* __restrict__ cwt, const int* __restrict__ target, float* __restrict__ aggw)
{
    int b = blockIdx.x, tid = threadIdx.x;
    __shared__ float s[26 * 256];
    for (int i = tid; i < 26 * 256; i += 256) s[i] = 0.f;
    __syncthreads();
    const int* tb = target + b * SEQ;
    for (int i = 0; i < SEQ; ++i) {
        int a = tb[i];
        s[a * 256 + tid] += cwt[i * 256 + tid];
    }
    __syncthreads();
    for (int i = tid; i < 26 * 256; i += 256)
        aggw[(long)b * 6656 + i] = s[i];
}

// Wc[(a*256+o*8+k)*128 + j] = sum_t emb[a,t+k] * w_fc[(o*121+t)*128 + j]
__global__ __launch_bounds__(128) void conv_wc_kernel(
    const float* __restrict__ emb, const float* __restrict__ w_fc, float* __restrict__ Wc)
{
    int o = blockIdx.x;      // 0..31
    int ak = blockIdx.y;     // 0..207
    int a = ak >> 3, k = ak & 7;
    int j = threadIdx.x;
    const float* wp = w_fc + (long)(o * 121) * 128 + j;
    const float* ep = emb + a * 128 + k;
    float s = 0.f;
    #pragma unroll 11
    for (int t = 0; t < 121; ++t) s += ep[t] * wp[t * 128];
    Wc[(long)(a * 256 + o * 8 + k) * 128 + j] = s;
}

// xtb[j] = fc1xt_b[j]
__global__ void xtb_init_kernel(const float* __restrict__ b_fc, float* __restrict__ xtb)
{
    xtb[threadIdx.x] = b_fc[threadIdx.x];
}

// xtb[j] += conv_b[o] * sum_t w_fc[(o*121+t)*128 + j]   (one block per o)
__global__ __launch_bounds__(128) void convb_fold_kernel(
    const float* __restrict__ w_fc, const float* __restrict__ conv_b, float* __restrict__ xtb)
{
    int o = blockIdx.x, j = threadIdx.x;
    const float* wp = w_fc + (long)(o * 121) * 128 + j;
    float s = 0.f;
    for (int t = 0; t < 121; ++t) s += wp[t * 128];
    atomicAdd(&xtb[j], s * conv_b[o]);
}

// xc[b, 128+j] = xtb[j]  (pre-init for split-K accumulate)
__global__ void xc_convbias_kernel(const float* __restrict__ xtb, float* __restrict__ xc)
{
    int idx = blockIdx.x * 256 + threadIdx.x;  // NB*128
    if (idx >= NB * 128) return;
    int b = idx >> 7, j = idx & 127;
    xc[(long)b * 384 + 128 + j] = xtb[j];
}

// ---------------------------------------------------------------------------
// FG branch: attention row 0 + LayerNorm
// ---------------------------------------------------------------------------
__global__ __launch_bounds__(256) void attn_ln_kernel(
    const float* __restrict__ Fb, const float* __restrict__ Kf, const float* __restrict__ Vf,
    const float* __restrict__ q0, const float* __restrict__ ln_g, const float* __restrict__ ln_b,
    float* __restrict__ out)
{
    int b = blockIdx.x, tid = threadIdx.x;
    __shared__ float qs[HID];
    __shared__ float sc[13];
    __shared__ float red[256];
    __shared__ float red2[256];
    __shared__ float rowv[HID];
    __shared__ float mean_s, inv_s;

    for (int d = tid; d < HID; d += 256) qs[d] = q0[(long)b * HID + d];
    __syncthreads();
    if (tid < 208) {
        int k = tid >> 4, sub = tid & 15;
        const float* kr = Kf + ((long)b * 13 + k) * HID;
        float p = 0.f;
        for (int d = sub; d < HID; d += 16) p += qs[d] * kr[d];
        red[tid] = p;
    }
    __syncthreads();
    if (tid < 208 && (tid & 15) == 0) {
        float s = 0.f;
        #pragma unroll
        for (int j = 0; j < 16; ++j) s += red[tid + j];
        sc[tid >> 4] = s * 0.0577350269189626f;  // 1/sqrt(300)
    }
    __syncthreads();
    if (tid == 0) {
        float mx = sc[0];
        for (int k = 1; k < 13; ++k) mx = fmaxf(mx, sc[k]);
        float ssum = 0.f;
        for (int k = 0; k < 13; ++k) { float e = expf(sc[k] - mx); sc[k] = e; ssum += e; }
        float inv = 1.0f / ssum;
        for (int k = 0; k < 13; ++k) sc[k] *= inv;
    }
    __syncthreads();
    for (int d = tid; d < HID; d += 256) {
        float v = Fb[((long)b * 13) * HID + d];
        #pragma unroll
        for (int k = 0; k < 13; ++k) v += sc[k] * Vf[((long)b * 13 + k) * HID + d];
        rowv[d] = v;
    }
    __syncthreads();
    float s1 = 0.f, s2 = 0.f;
    for (int d = tid; d < HID; d += 256) { float v = rowv[d]; s1 += v; s2 += v * v; }
    red[tid] = s1; red2[tid] = s2;
    __syncthreads();
    for (int s = 128; s > 0; s >>= 1) {
        if (tid < s) { red[tid] += red[tid + s]; red2[tid] += red2[tid + s]; }
        __syncthreads();
    }
    if (tid == 0) {
        float mean = red[0] / (float)HID;
        float var = red2[0] / (float)HID - mean * mean;
        mean_s = mean;
        inv_s = 1.0f / sqrtf(var + 1e-5f);
    }
    __syncthreads();
    for (int d = tid; d < HID; d += 256)
        out[(long)b * HID + d] = (rowv[d] - mean_s) * inv_s * ln_g[d] + ln_b[d];
}

// ---------------------------------------------------------------------------
// final: out[b] = X[b,:512] . out_w + out_b
// ---------------------------------------------------------------------------
__global__ __launch_bounds__(256) void final_out_kernel(
    const float* __restrict__ X, const float* __restrict__ w,
    const float* __restrict__ bias, float* __restrict__ out)
{
    int b = blockIdx.x, tid = threadIdx.x;
    __shared__ float red[256];
    float p = X[(long)b * 512 + tid] * w[tid] + X[(long)b * 512 + tid + 256] * w[tid + 256];
    red[tid] = p;
    __syncthreads();
    for (int s = 128; s > 0; s >>= 1) {
        if (tid < s) red[tid] += red[tid + s];
        __syncthreads();
    }
    if (tid == 0) out[b] = red[0] + bias[0];
}

// ---------------------------------------------------------------------------
// Host launcher
// ---------------------------------------------------------------------------
extern "C" void kernel_launch(void* const* d_in, const int* in_sizes, int n_in,
                              void* d_out, int out_size, void* d_ws, size_t ws_size,
                              hipStream_t stream)
{
    const float* x        = (const float*)d_in[0];
    const int*   ei       = (const int*)d_in[1];
    const int*   batch    = (const int*)d_in[2];
    const int*   target   = (const int*)d_in[3];
    const float* embs     = (const float*)d_in[4];
    const float* W1       = (const float*)d_in[5];
    const float* b1       = (const float*)d_in[6];
    const float* W2       = (const float*)d_in[7];
    const float* b2       = (const float*)d_in[8];
    const float* W3       = (const float*)d_in[9];
    const float* b3       = (const float*)d_in[10];
    const float* fc_g1_w  = (const float*)d_in[11];
    const float* fc_g1_b  = (const float*)d_in[12];
    const float* fc_g2_w  = (const float*)d_in[13];
    const float* fc_g2_b  = (const float*)d_in[14];
    const float* emb_xt   = (const float*)d_in[15];
    const float* conv_w   = (const float*)d_in[16];
    const float* conv_b   = (const float*)d_in[17];
    const float* fc1xt_w  = (const float*)d_in[18];
    const float* fc1xt_b  = (const float*)d_in[19];
    const float* fg_lin_w = (const float*)d_in[20];
    const float* fg_lin_b = (const float*)d_in[21];
    const float* Wq       = (const float*)d_in[22];
    const float* Wk       = (const float*)d_in[23];
    const float* Wv       = (const float*)d_in[24];
    const float* ln_g     = (const float*)d_in[25];
    const float* ln_b     = (const float*)d_in[26];
    const float* fg_out_w = (const float*)d_in[27];
    const float* fg_out_b = (const float*)d_in[28];
    const float* fc1_w    = (const float*)d_in[29];
    const float* fc1_b    = (const float*)d_in[30];
    const float* fc2_w    = (const float*)d_in[31];
    const float* fc2_b    = (const float*)d_in[32];
    const float* out_w    = (const float*)d_in[33];
    const float* out_b    = (const float*)d_in[34];

    const int* src = ei;
    const int* dst = ei + NEDGES;

    float* ws   = (float*)d_ws;
    float* bufA = ws;                    // 31,200,000 floats
    float* bufT = bufA + 31200000;       // 31,200,000 floats
    float* aux  = bufT + 31200000;
    int*   deg     = (int*)aux;          // 100000 (reused as CSR cursor)
    float* dis     = aux + 100000;       // 100000
    float* selfc   = aux + 200000;       // 100000
    int*   off     = (int*)(aux + 300000);   // 100004
    int*   csr_src = (int*)(aux + 400004);   // 400000
    float* csr_w   = aux + 800004;       // 400000
    float* g       = aux + 1200004;      // 319488 (1024x312)
    float* G1      = aux + 1519492;      // 1,048,576 (1024x1024)
    float* xc      = aux + 2568068;      // 393,216 (1024x384)
    float* F2      = aux + 2961284;      // 524,288 (1024x512)
    // aliases carved from bufT (free after GCN layer-3 agg):
    float* cwt   = bufT;                 // 256,000
    float* aggw  = bufT + 256000;        // 6,815,744
    float* Fbuf  = bufT + 7071744;       // 3,993,600 (13312x300)
    float* Kbuf  = bufT + 11065344;      // 3,993,600
    float* Vbuf  = bufT + 15058944;      // 3,993,600
    float* Qbuf  = bufT + 19052544;      // 307,200 (1024x300)
    float* f2row = bufT + 19359744;      // 307,200
    // aliases carved from bufA (free after pool_max):
    float* Wc    = bufA;                 // 851,968 (6656x128)
    float* xtb   = bufA + 851968;        // 128

    // ---- degree / norms / CSR ----
    hipMemsetAsync(deg, 0, NNODES * sizeof(int), stream);
    deg_kernel<<<(NEDGES + 255) / 256, 256, 0, stream>>>(dst, deg, NEDGES);
    dis_kernel<<<(NNODES + 255) / 256, 256, 0, stream>>>(deg, dis, selfc, NNODES);
    scan_kernel<<<1, 1024, 0, stream>>>(deg, off);
    cur_init_kernel<<<(NNODES + 255) / 256, 256, 0, stream>>>(off, deg, NNODES);
    fill_csr_kernel<<<(NEDGES + 255) / 256, 256, 0, stream>>>(src, dst, dis, deg, csr_src, csr_w, NEDGES);

    // ---- GCN layers: GEMM -> fused gather-agg(+bias+relu) ----
    launch_gemm(x, W1, nullptr, bufT, NNODES, 78, 78, 78, 78, 78, 0, stream);
    gcn_agg_fused<<<dim3((NNODES + 3) / 4, 2), 256, 0, stream>>>(bufT, off, csr_src, csr_w, selfc, b1, bufA, 78);

    launch_gemm(bufA, W2, nullptr, bufT, NNODES, 156, 78, 78, 156, 156, 0, stream);
    gcn_agg_fused<<<dim3((NNODES + 3) / 4, 3), 256, 0, stream>>>(bufT, off, csr_src, csr_w, selfc, b2, bufA, 156);

    launch_gemm(bufA, W3, nullptr, bufT, NNODES, 312, 156, 156, 312, 312, 0, stream);
    gcn_agg_fused<<<dim3((NNODES + 3) / 4, 5), 256, 0, stream>>>(bufT, off, csr_src, csr_w, selfc, b3, bufA, 312);

    // ---- global max pool + graph MLP ----
    pool_max_kernel<<<NB, 256, 0, stream>>>(bufA, batch, g);
    launch_gemm(g, fc_g1_w, fc_g1_b, G1, NB, 1024, 312, 312, 1024, 1024, 1, stream);
    launch_gemm(G1, fc_g2_w, fc_g2_b, xc, NB, 128, 1024, 1024, 128, 384, 0, stream);

    // ---- conv branch (folded into a single split-K GEMM) ----
    conv_transpose_kernel<<<(256000 + 255) / 256, 256, 0, stream>>>(conv_w, cwt);
    conv_agg_kernel<<<NB, 256, 0, stream>>>(cwt, target, aggw);
    conv_wc_kernel<<<dim3(32, 208), 128, 0, stream>>>(emb_xt, fc1xt_w, Wc);
    xtb_init_kernel<<<1, 128, 0, stream>>>(fc1xt_b, xtb);
    convb_fold_kernel<<<32, 128, 0, stream>>>(fc1xt_w, conv_b, xtb);
    xc_convbias_kernel<<<(NB * 128 + 255) / 256, 256, 0, stream>>>(xtb, xc);
    {
        dim3 grid(2, 16, 13);  // N=128, M=1024, K=6656 in 13 chunks of 512
        gemm_splitk_kernel<<<grid, 256, 0, stream>>>(aggw, Wc, xc + 128, NB, 128, 6656, 6656, 128, 384, 512);
    }

    // ---- FG branch ----
    launch_gemm(embs, fg_lin_w, fg_lin_b, Fbuf, NB * 13, HID, 133, 133, HID, HID, 0, stream);
    launch_gemm(Fbuf, Wk, nullptr, Kbuf, NB * 13, HID, HID, HID, HID, HID, 0, stream);
    launch_gemm(Fbuf, Wv, nullptr, Vbuf, NB * 13, HID, HID, HID, HID, HID, 0, stream);
    launch_gemm(Fbuf, Wq, nullptr, Qbuf, NB, HID, HID, 13 * HID, HID, HID, 0, stream);
    attn_ln_kernel<<<NB, 256, 0, stream>>>(Fbuf, Kbuf, Vbuf, Qbuf, ln_g, ln_b, f2row);
    launch_gemm(f2row, fg_out_w, fg_out_b, xc + 256, NB, 128, HID, HID, 128, 384, 0, stream);

    // ---- head ----
    launch_gemm(xc, fc1_w, fc1_b, G1, NB, 1024, 384, 384, 1024, 1024, 1, stream);
    launch_gemm(G1, fc2_w, fc2_b, F2, NB, 512, 1024, 1024, 512, 512, 1, stream);
    final_out_kernel<<<NB, 256, 0, stream>>>(F2, out_w, out_b, (float*)d_out);
}

// Round 4
// 1327.097 us; speedup vs baseline: 2.2348x; 1.7955x over previous
//
#include <hip/hip_runtime.h>
#include <hip/hip_bf16.h>
#include <math.h>

// ---------------------------------------------------------------------------
// Problem constants
// ---------------------------------------------------------------------------
#define NNODES 100000
#define NEDGES 400000
#define NB     1024
#define SEQ    1000
#define HID    300

typedef __attribute__((ext_vector_type(8))) short short8;   // 8 bf16 (4 VGPRs)
typedef __attribute__((ext_vector_type(4))) float f32x4;    // MFMA acc

// ---------------------------------------------------------------------------
// fp32 [M][K] -> bf16 [M][Kpad] (zero-padded)
// ---------------------------------------------------------------------------
__global__ void cvt_pad_kernel(const float* __restrict__ in, __hip_bfloat16* __restrict__ out,
                               int M, int K, int Kpad)
{
    long idx = (long)blockIdx.x * 256 + threadIdx.x;
    if (idx >= (long)M * Kpad) return;
    int m = idx / Kpad, k = idx % Kpad;
    out[idx] = __float2bfloat16(k < K ? in[(long)m * K + k] : 0.f);
}

// fp32 [K][N] row-major -> bf16 Bt [N][Kpad] (zero-padded)
__global__ void transpose_cvt_kernel(const float* __restrict__ in, __hip_bfloat16* __restrict__ out,
                                     int K, int N, int Kpad)
{
    long idx = (long)blockIdx.x * 256 + threadIdx.x;
    if (idx >= (long)N * Kpad) return;
    int n = idx / Kpad, k = idx % Kpad;
    out[idx] = __float2bfloat16(k < K ? in[(long)k * N + n] : 0.f);
}

// ---------------------------------------------------------------------------
// BF16 MFMA GEMM (TN): C = act(A @ Bt^T + bias)
// A: [M][lda] bf16 (lda >= Kpad), Bt: [N][Kpad] bf16 (row n = col n of B).
// Block 256 thr = 4 waves (2x2), tile 64x64, per wave 32x32 via 2x2 mfma 16x16x32.
// outbf: write bf16 (cols N..Npad_out zero-filled) else fp32.
// chunk>0: split-K, fp32 atomicAdd into pre-initialized C.
// ---------------------------------------------------------------------------
__global__ __launch_bounds__(256) void gemm_bf16_kernel(
    const __hip_bfloat16* __restrict__ A, const __hip_bfloat16* __restrict__ Bt,
    const float* __restrict__ bias, void* __restrict__ C,
    int M, int N, int Kpad, int lda, int ldc, int Npad_out,
    int relu, int outbf, int chunk)
{
    __shared__ __align__(16) __hip_bfloat16 As[64][40];  // 32 data + 8 pad
    __shared__ __align__(16) __hip_bfloat16 Bs[64][40];
    int tid = threadIdx.x;
    int wave = tid >> 6, lane = tid & 63;
    int wm = wave >> 1, wn = wave & 1;
    int quad = lane >> 4, l16 = lane & 15;
    int row0 = blockIdx.y * 64, col0 = blockIdx.x * 64;

    int kbeg = 0, kend = Kpad;
    if (chunk > 0) { kbeg = blockIdx.z * chunk; kend = kbeg + chunk; if (kend > Kpad) kend = Kpad; }

    f32x4 acc[2][2];
    #pragma unroll
    for (int i = 0; i < 2; ++i)
        #pragma unroll
        for (int j = 0; j < 2; ++j) acc[i][j] = (f32x4){0.f, 0.f, 0.f, 0.f};

    int r = tid >> 2, cch = (tid & 3) * 8;   // stage: 64 rows x 4 chunks of 8 bf16

    for (int k0 = kbeg; k0 < kend; k0 += 32) {
        uint4 av = {0u, 0u, 0u, 0u};
        if (row0 + r < M) av = *(const uint4*)(A + (size_t)(row0 + r) * lda + k0 + cch);
        *(uint4*)(&As[r][cch]) = av;
        uint4 bv = {0u, 0u, 0u, 0u};
        if (col0 + r < N) bv = *(const uint4*)(Bt + (size_t)(col0 + r) * Kpad + k0 + cch);
        *(uint4*)(&Bs[r][cch]) = bv;
        __syncthreads();

        short8 a0 = *(const short8*)(&As[wm * 32 + l16][quad * 8]);
        short8 a1 = *(const short8*)(&As[wm * 32 + 16 + l16][quad * 8]);
        short8 b0 = *(const short8*)(&Bs[wn * 32 + l16][quad * 8]);
        short8 b1 = *(const short8*)(&Bs[wn * 32 + 16 + l16][quad * 8]);
        acc[0][0] = __builtin_amdgcn_mfma_f32_16x16x32_bf16(a0, b0, acc[0][0], 0, 0, 0);
        acc[0][1] = __builtin_amdgcn_mfma_f32_16x16x32_bf16(a0, b1, acc[0][1], 0, 0, 0);
        acc[1][0] = __builtin_amdgcn_mfma_f32_16x16x32_bf16(a1, b0, acc[1][0], 0, 0, 0);
        acc[1][1] = __builtin_amdgcn_mfma_f32_16x16x32_bf16(a1, b1, acc[1][1], 0, 0, 0);
        __syncthreads();
    }

    #pragma unroll
    for (int ti = 0; ti < 2; ++ti) {
        int rbase = row0 + wm * 32 + ti * 16 + quad * 4;
        #pragma unroll
        for (int tj = 0; tj < 2; ++tj) {
            int cc = col0 + wn * 32 + tj * 16 + l16;
            if (cc >= Npad_out) continue;
            #pragma unroll
            for (int reg = 0; reg < 4; ++reg) {
                int rr = rbase + reg;
                if (rr >= M) continue;
                float v = acc[ti][tj][reg];
                if (chunk > 0) {
                    if (cc < N) atomicAdd((float*)C + (size_t)rr * ldc + cc, v);
                } else {
                    float ov = 0.f;
                    if (cc < N) {
                        if (bias) v += bias[cc];
                        if (relu) v = fmaxf(v, 0.f);
                        ov = v;
                    }
                    if (outbf) ((__hip_bfloat16*)C)[(size_t)rr * ldc + cc] = __float2bfloat16(ov);
                    else       ((float*)C)[(size_t)rr * ldc + cc] = ov;
                }
            }
        }
    }
}

static void launch_gemm_bf16(const __hip_bfloat16* A, const __hip_bfloat16* Bt, const float* bias,
                             void* C, int M, int N, int Kpad, int lda, int ldc, int Npad_out,
                             int relu, int outbf, int splitz, hipStream_t stream)
{
    int cover = N > Npad_out ? N : Npad_out;
    int chunk = (splitz > 1) ? (Kpad / splitz) : 0;
    dim3 grid((cover + 63) / 64, (M + 63) / 64, splitz > 1 ? splitz : 1);
    gemm_bf16_kernel<<<grid, 256, 0, stream>>>(A, Bt, bias, C, M, N, Kpad, lda, ldc, Npad_out,
                                               relu, outbf, chunk);
}

// ---------------------------------------------------------------------------
// GCN: degree, norms, CSR build
// ---------------------------------------------------------------------------
__global__ void deg_kernel(const int* __restrict__ dst, int* __restrict__ deg, int E)
{
    int e = blockIdx.x * 256 + threadIdx.x;
    if (e < E) atomicAdd(&deg[dst[e]], 1);
}

__global__ void dis_kernel(const int* __restrict__ deg, float* __restrict__ dis,
                           float* __restrict__ selfc, int n)
{
    int i = blockIdx.x * 256 + threadIdx.x;
    if (i < n) {
        float d = (float)deg[i] + 1.0f;
        float r = 1.0f / sqrtf(d);
        dis[i] = r;
        selfc[i] = r * r;
    }
}

__global__ __launch_bounds__(1024) void scan_kernel(const int* __restrict__ deg,
                                                    int* __restrict__ off)
{
    __shared__ int ssum[1024];
    int tid = threadIdx.x;
    const int CH = (NNODES + 1023) / 1024;  // 98
    int start = tid * CH;
    int end = start + CH; if (end > NNODES) end = NNODES;
    int s = 0;
    for (int i = start; i < end && i < NNODES; ++i) s += deg[i];
    ssum[tid] = s;
    __syncthreads();
    for (int d = 1; d < 1024; d <<= 1) {
        int v = ssum[tid];
        int add = (tid >= d) ? ssum[tid - d] : 0;
        __syncthreads();
        ssum[tid] = v + add;
        __syncthreads();
    }
    int pre = ssum[tid] - s;
    for (int i = start; i < end && i < NNODES; ++i) { off[i] = pre; pre += deg[i]; }
    if (tid == 0) off[NNODES] = NEDGES;
}

__global__ void cur_init_kernel(const int* __restrict__ off, int* __restrict__ cur, int n)
{
    int i = blockIdx.x * 256 + threadIdx.x;
    if (i < n) cur[i] = off[i];
}

__global__ void fill_csr_kernel(const int* __restrict__ src, const int* __restrict__ dst,
                                const float* __restrict__ dis, int* __restrict__ cur,
                                int* __restrict__ csr_src, float* __restrict__ csr_w, int E)
{
    int e = blockIdx.x * 256 + threadIdx.x;
    if (e >= E) return;
    int s = src[e], d = dst[e];
    int p = atomicAdd(&cur[d], 1);
    csr_src[p] = s;
    csr_w[p] = dis[s] * dis[d];
}

// ---------------------------------------------------------------------------
// Fused GCN aggregation (bf16 in, bf16 padded out)
// ---------------------------------------------------------------------------
__global__ __launch_bounds__(256) void gcn_agg_bf16(
    const __hip_bfloat16* __restrict__ T, const int* __restrict__ off,
    const int* __restrict__ csr_src, const float* __restrict__ csr_w,
    const float* __restrict__ selfc, const float* __restrict__ bias,
    __hip_bfloat16* __restrict__ out, int F, int Fpad)
{
    int wave = threadIdx.x >> 6;
    int lane = threadIdx.x & 63;
    int node = blockIdx.x * 4 + wave;
    if (node >= NNODES) return;
    int f = blockIdx.y * 64 + lane;
    if (f >= Fpad) return;
    float r = 0.f;
    if (f < F) {
        int s0 = off[node], s1 = off[node + 1];
        float acc = __bfloat162float(T[(size_t)node * F + f]) * selfc[node];
        for (int e = s0; e < s1; ++e)
            acc += __bfloat162float(T[(size_t)csr_src[e] * F + f]) * csr_w[e];
        r = fmaxf(acc + bias[f], 0.f);
    }
    out[(size_t)node * Fpad + f] = __float2bfloat16(r);
}

// ---------------------------------------------------------------------------
// segment max pool (bf16 in [NNODES][320], bf16 out [NB][320]); batch sorted
// ---------------------------------------------------------------------------
__global__ __launch_bounds__(256) void pool_max_bf16(
    const __hip_bfloat16* __restrict__ H, const int* __restrict__ batch,
    __hip_bfloat16* __restrict__ g)
{
    int b = blockIdx.x;
    int lo = 0, hi = NNODES;
    while (lo < hi) { int mid = (lo + hi) >> 1; if (batch[mid] < b) lo = mid + 1; else hi = mid; }
    int s = lo;
    hi = NNODES;
    while (lo < hi) { int mid = (lo + hi) >> 1; if (batch[mid] < b + 1) lo = mid + 1; else hi = mid; }
    int e = lo;
    for (int f = threadIdx.x; f < 320; f += 256) {
        float m = 0.f;  // pad cols are 0; post-relu values >= 0
        for (int i = s; i < e; ++i) m = fmaxf(m, __bfloat162float(H[(size_t)i * 320 + f]));
        g[(size_t)b * 320 + f] = __float2bfloat16(m);
    }
}

// ---------------------------------------------------------------------------
// Conv branch: bucketing + weight folding
// ---------------------------------------------------------------------------
__global__ void conv_transpose_kernel(const float* __restrict__ w, float* __restrict__ wt)
{
    int idx = blockIdx.x * 256 + threadIdx.x;
    if (idx >= 256000) return;
    int o = idx / 8000;
    int rem = idx - o * 8000;
    int i = rem >> 3, k = rem & 7;
    wt[i * 256 + o * 8 + k] = w[idx];
}

// aggw[b][a*256+o*8+k] = sum_{i: target[b,i]==a} conv_w[o,i,k]   (bf16 out)
__global__ __launch_bounds__(256) void conv_agg_kernel(
    const float* __restrict__ cwt, const int* __restrict__ target,
    __hip_bfloat16* __restrict__ aggw)
{
    int b = blockIdx.x, tid = threadIdx.x;
    __shared__ float s[26 * 256];
    for (int i = tid; i < 26 * 256; i += 256) s[i] = 0.f;
    __syncthreads();
    const int* tb = target + b * SEQ;
    for (int i = 0; i < SEQ; ++i) {
        int a = tb[i];
        s[a * 256 + tid] += cwt[i * 256 + tid];
    }
    __syncthreads();
    for (int i = tid; i < 26 * 256; i += 256)
        aggw[(size_t)b * 6656 + i] = __float2bfloat16(s[i]);
}

// Wc[(a*256+o*8+k)*128 + j] = sum_t emb[a,t+k] * w_fc[(o*121+t)*128 + j]
__global__ __launch_bounds__(128) void conv_wc_kernel(
    const float* __restrict__ emb, const float* __restrict__ w_fc, float* __restrict__ Wc)
{
    int o = blockIdx.x;      // 0..31
    int ak = blockIdx.y;     // 0..207
    int a = ak >> 3, k = ak & 7;
    int j = threadIdx.x;
    const float* wp = w_fc + (long)(o * 121) * 128 + j;
    const float* ep = emb + a * 128 + k;
    float s = 0.f;
    #pragma unroll 11
    for (int t = 0; t < 121; ++t) s += ep[t] * wp[t * 128];
    Wc[(long)(a * 256 + o * 8 + k) * 128 + j] = s;
}

__global__ void xtb_init_kernel(const float* __restrict__ b_fc, float* __restrict__ xtb)
{
    xtb[threadIdx.x] = b_fc[threadIdx.x];
}

__global__ __launch_bounds__(128) void convb_fold_kernel(
    const float* __restrict__ w_fc, const float* __restrict__ conv_b, float* __restrict__ xtb)
{
    int o = blockIdx.x, j = threadIdx.x;
    const float* wp = w_fc + (long)(o * 121) * 128 + j;
    float s = 0.f;
    for (int t = 0; t < 121; ++t) s += wp[t * 128];
    atomicAdd(&xtb[j], s * conv_b[o]);
}

__global__ void xc_convbias_kernel(const float* __restrict__ xtb, float* __restrict__ xc)
{
    int idx = blockIdx.x * 256 + threadIdx.x;
    if (idx >= NB * 128) return;
    int b = idx >> 7, j = idx & 127;
    xc[(long)b * 384 + 128 + j] = xtb[j];
}

// ---------------------------------------------------------------------------
// FG branch: attention row 0 + LayerNorm (bf16 in, bf16 padded out)
// Fb: [13312][320], Kf/Vf: [13312][320], q0: [NB][320]
// ---------------------------------------------------------------------------
__global__ __launch_bounds__(256) void attn_ln_kernel(
    const __hip_bfloat16* __restrict__ Fb, const __hip_bfloat16* __restrict__ Kf,
    const __hip_bfloat16* __restrict__ Vf, const __hip_bfloat16* __restrict__ q0,
    const float* __restrict__ ln_g, const float* __restrict__ ln_b,
    __hip_bfloat16* __restrict__ out)
{
    int b = blockIdx.x, tid = threadIdx.x;
    __shared__ float qs[HID];
    __shared__ float sc[13];
    __shared__ float red[256];
    __shared__ float red2[256];
    __shared__ float rowv[HID];
    __shared__ float mean_s, inv_s;

    for (int d = tid; d < HID; d += 256) qs[d] = __bfloat162float(q0[(size_t)b * 320 + d]);
    __syncthreads();
    if (tid < 208) {
        int k = tid >> 4, sub = tid & 15;
        const __hip_bfloat16* kr = Kf + ((size_t)b * 13 + k) * 320;
        float p = 0.f;
        for (int d = sub; d < HID; d += 16) p += qs[d] * __bfloat162float(kr[d]);
        red[tid] = p;
    }
    __syncthreads();
    if (tid < 208 && (tid & 15) == 0) {
        float s = 0.f;
        #pragma unroll
        for (int j = 0; j < 16; ++j) s += red[tid + j];
        sc[tid >> 4] = s * 0.0577350269189626f;  // 1/sqrt(300)
    }
    __syncthreads();
    if (tid == 0) {
        float mx = sc[0];
        for (int k = 1; k < 13; ++k) mx = fmaxf(mx, sc[k]);
        float ssum = 0.f;
        for (int k = 0; k < 13; ++k) { float e = expf(sc[k] - mx); sc[k] = e; ssum += e; }
        float inv = 1.0f / ssum;
        for (int k = 0; k < 13; ++k) sc[k] *= inv;
    }
    __syncthreads();
    for (int d = tid; d < HID; d += 256) {
        float v = __bfloat162float(Fb[((size_t)b * 13) * 320 + d]);
        #pragma unroll
        for (int k = 0; k < 13; ++k)
            v += sc[k] * __bfloat162float(Vf[((size_t)b * 13 + k) * 320 + d]);
        rowv[d] = v;
    }
    __syncthreads();
    float s1 = 0.f, s2 = 0.f;
    for (int d = tid; d < HID; d += 256) { float v = rowv[d]; s1 += v; s2 += v * v; }
    red[tid] = s1; red2[tid] = s2;
    __syncthreads();
    for (int s = 128; s > 0; s >>= 1) {
        if (tid < s) { red[tid] += red[tid + s]; red2[tid] += red2[tid + s]; }
        __syncthreads();
    }
    if (tid == 0) {
        float mean = red[0] / (float)HID;
        float var = red2[0] / (float)HID - mean * mean;
        mean_s = mean;
        inv_s = 1.0f / sqrtf(var + 1e-5f);
    }
    __syncthreads();
    for (int d = tid; d < 320; d += 256) {
        float v = 0.f;
        if (d < HID) v = (rowv[d] - mean_s) * inv_s * ln_g[d] + ln_b[d];
        out[(size_t)b * 320 + d] = __float2bfloat16(v);
    }
}

// ---------------------------------------------------------------------------
// final: out[b] = X[b,:512] . out_w + out_b   (fp32)
// ---------------------------------------------------------------------------
__global__ __launch_bounds__(256) void final_out_kernel(
    const float* __restrict__ X, const float* __restrict__ w,
    const float* __restrict__ bias, float* __restrict__ out)
{
    int b = blockIdx.x, tid = threadIdx.x;
    __shared__ float red[256];
    float p = X[(long)b * 512 + tid] * w[tid] + X[(long)b * 512 + tid + 256] * w[tid + 256];
    red[tid] = p;
    __syncthreads();
    for (int s = 128; s > 0; s >>= 1) {
        if (tid < s) red[tid] += red[tid + s];
        __syncthreads();
    }
    if (tid == 0) out[b] = red[0] + bias[0];
}

// ---------------------------------------------------------------------------
// Host launcher
// ---------------------------------------------------------------------------
extern "C" void kernel_launch(void* const* d_in, const int* in_sizes, int n_in,
                              void* d_out, int out_size, void* d_ws, size_t ws_size,
                              hipStream_t stream)
{
    const float* x        = (const float*)d_in[0];
    const int*   ei       = (const int*)d_in[1];
    const int*   batch    = (const int*)d_in[2];
    const int*   target   = (const int*)d_in[3];
    const float* embs     = (const float*)d_in[4];
    const float* W1       = (const float*)d_in[5];
    const float* b1       = (const float*)d_in[6];
    const float* W2       = (const float*)d_in[7];
    const float* b2       = (const float*)d_in[8];
    const float* W3       = (const float*)d_in[9];
    const float* b3       = (const float*)d_in[10];
    const float* fc_g1_w  = (const float*)d_in[11];
    const float* fc_g1_b  = (const float*)d_in[12];
    const float* fc_g2_w  = (const float*)d_in[13];
    const float* fc_g2_b  = (const float*)d_in[14];
    const float* emb_xt   = (const float*)d_in[15];
    const float* conv_w   = (const float*)d_in[16];
    const float* conv_b   = (const float*)d_in[17];
    const float* fc1xt_w  = (const float*)d_in[18];
    const float* fc1xt_b  = (const float*)d_in[19];
    const float* fg_lin_w = (const float*)d_in[20];
    const float* fg_lin_b = (const float*)d_in[21];
    const float* Wq       = (const float*)d_in[22];
    const float* Wk       = (const float*)d_in[23];
    const float* Wv       = (const float*)d_in[24];
    const float* ln_g     = (const float*)d_in[25];
    const float* ln_b     = (const float*)d_in[26];
    const float* fg_out_w = (const float*)d_in[27];
    const float* fg_out_b = (const float*)d_in[28];
    const float* fc1_w    = (const float*)d_in[29];
    const float* fc1_b    = (const float*)d_in[30];
    const float* fc2_w    = (const float*)d_in[31];
    const float* fc2_b    = (const float*)d_in[32];
    const float* out_w    = (const float*)d_in[33];
    const float* out_b    = (const float*)d_in[34];

    const int* src = ei;
    const int* dst = ei + NEDGES;
    typedef __hip_bfloat16 bf;

    // ---- workspace carve (256-B aligned bump allocator) ----
    char* p = (char*)d_ws;
    auto alloc = [&](size_t bytes) { char* r = p; p += (bytes + 255) & ~(size_t)255; return r; };
    bf*   xb      = (bf*)alloc((size_t)NNODES * 96 * 2);
    bf*   T       = (bf*)alloc((size_t)NNODES * 312 * 2);
    bf*   H       = (bf*)alloc((size_t)NNODES * 320 * 2);
    int*  deg     = (int*)alloc(NNODES * 4);
    float* dis    = (float*)alloc(NNODES * 4);
    float* selfc  = (float*)alloc(NNODES * 4);
    int*  off     = (int*)alloc((NNODES + 1) * 4);
    int*  csr_src = (int*)alloc(NEDGES * 4);
    float* csr_w  = (float*)alloc(NEDGES * 4);
    bf*   w1t     = (bf*)alloc(78 * 96 * 2);
    bf*   w2t     = (bf*)alloc(156 * 96 * 2);
    bf*   w3t     = (bf*)alloc(312 * 160 * 2);
    bf*   fcg1t   = (bf*)alloc(1024 * 320 * 2);
    bf*   fcg2t   = (bf*)alloc(128 * 1024 * 2);
    bf*   fglint  = (bf*)alloc(300 * 160 * 2);
    bf*   wkt     = (bf*)alloc(300 * 320 * 2);
    bf*   wvt     = (bf*)alloc(300 * 320 * 2);
    bf*   wqt     = (bf*)alloc(300 * 320 * 2);
    bf*   fgoutt  = (bf*)alloc(128 * 320 * 2);
    bf*   fc1t    = (bf*)alloc(1024 * 384 * 2);
    bf*   fc2t    = (bf*)alloc(512 * 1024 * 2);
    bf*   g       = (bf*)alloc((size_t)NB * 320 * 2);
    bf*   G1b     = (bf*)alloc((size_t)NB * 1024 * 2);
    bf*   embsb   = (bf*)alloc((size_t)NB * 13 * 160 * 2);
    bf*   Fbuf    = (bf*)alloc((size_t)NB * 13 * 320 * 2);
    bf*   Kbuf    = (bf*)alloc((size_t)NB * 13 * 320 * 2);
    bf*   Vbuf    = (bf*)alloc((size_t)NB * 13 * 320 * 2);
    bf*   Qbuf    = (bf*)alloc((size_t)NB * 320 * 2);
    bf*   f2row   = (bf*)alloc((size_t)NB * 320 * 2);
    float* xc     = (float*)alloc((size_t)NB * 384 * 4);
    bf*   xcb     = (bf*)alloc((size_t)NB * 384 * 2);
    float* F2     = (float*)alloc((size_t)NB * 512 * 4);
    float* cwt    = (float*)alloc(256000 * 4);
    bf*   aggwb   = (bf*)alloc((size_t)NB * 6656 * 2);
    float* Wc     = (float*)alloc((size_t)6656 * 128 * 4);
    bf*   Wct     = (bf*)alloc((size_t)128 * 6656 * 2);
    float* xtb    = (float*)alloc(128 * 4);

    // ---- degree / norms / CSR ----
    hipMemsetAsync(deg, 0, NNODES * sizeof(int), stream);
    deg_kernel<<<(NEDGES + 255) / 256, 256, 0, stream>>>(dst, deg, NEDGES);
    dis_kernel<<<(NNODES + 255) / 256, 256, 0, stream>>>(deg, dis, selfc, NNODES);
    scan_kernel<<<1, 1024, 0, stream>>>(deg, off);
    cur_init_kernel<<<(NNODES + 255) / 256, 256, 0, stream>>>(off, deg, NNODES);
    fill_csr_kernel<<<(NEDGES + 255) / 256, 256, 0, stream>>>(src, dst, dis, deg, csr_src, csr_w, NEDGES);

    // ---- weight transposes / input converts ----
    auto tcvt = [&](const float* W, bf* Bt, int K, int N, int Kpad) {
        long tot = (long)N * Kpad;
        transpose_cvt_kernel<<<(tot + 255) / 256, 256, 0, stream>>>(W, Bt, K, N, Kpad);
    };
    tcvt(W1, w1t, 78, 78, 96);
    tcvt(W2, w2t, 78, 156, 96);
    tcvt(W3, w3t, 156, 312, 160);
    tcvt(fc_g1_w, fcg1t, 312, 1024, 320);
    tcvt(fc_g2_w, fcg2t, 1024, 128, 1024);
    tcvt(fg_lin_w, fglint, 133, 300, 160);
    tcvt(Wk, wkt, 300, 300, 320);
    tcvt(Wv, wvt, 300, 300, 320);
    tcvt(Wq, wqt, 300, 300, 320);
    tcvt(fg_out_w, fgoutt, 300, 128, 320);
    tcvt(fc1_w, fc1t, 384, 1024, 384);
    tcvt(fc2_w, fc2t, 1024, 512, 1024);
    cvt_pad_kernel<<<((long)NNODES * 96 + 255) / 256, 256, 0, stream>>>(x, xb, NNODES, 78, 96);
    cvt_pad_kernel<<<((long)NB * 13 * 160 + 255) / 256, 256, 0, stream>>>(embs, embsb, NB * 13, 133, 160);

    // ---- GCN layers: MFMA GEMM -> fused gather-agg(+bias+relu), all bf16 ----
    launch_gemm_bf16(xb, w1t, nullptr, T, NNODES, 78, 96, 96, 78, 78, 0, 1, 1, stream);
    gcn_agg_bf16<<<dim3((NNODES + 3) / 4, 2), 256, 0, stream>>>(T, off, csr_src, csr_w, selfc, b1, H, 78, 96);

    launch_gemm_bf16(H, w2t, nullptr, T, NNODES, 156, 96, 96, 156, 156, 0, 1, 1, stream);
    gcn_agg_bf16<<<dim3((NNODES + 3) / 4, 3), 256, 0, stream>>>(T, off, csr_src, csr_w, selfc, b2, H, 156, 160);

    launch_gemm_bf16(H, w3t, nullptr, T, NNODES, 312, 160, 160, 312, 312, 0, 1, 1, stream);
    gcn_agg_bf16<<<dim3((NNODES + 3) / 4, 5), 256, 0, stream>>>(T, off, csr_src, csr_w, selfc, b3, H, 312, 320);

    // ---- global max pool + graph MLP ----
    pool_max_bf16<<<NB, 256, 0, stream>>>(H, batch, g);
    launch_gemm_bf16(g, fcg1t, fc_g1_b, G1b, NB, 1024, 320, 320, 1024, 1024, 1, 1, 1, stream);
    launch_gemm_bf16(G1b, fcg2t, fc_g2_b, xc, NB, 128, 1024, 1024, 384, 128, 0, 0, 1, stream);

    // ---- conv branch (folded; split-K MFMA accumulates into xc cols 128..255) ----
    conv_transpose_kernel<<<(256000 + 255) / 256, 256, 0, stream>>>(conv_w, cwt);
    conv_agg_kernel<<<NB, 256, 0, stream>>>(cwt, target, aggwb);
    conv_wc_kernel<<<dim3(32, 208), 128, 0, stream>>>(emb_xt, fc1xt_w, Wc);
    transpose_cvt_kernel<<<((long)128 * 6656 + 255) / 256, 256, 0, stream>>>(Wc, Wct, 6656, 128, 6656);
    xtb_init_kernel<<<1, 128, 0, stream>>>(fc1xt_b, xtb);
    convb_fold_kernel<<<32, 128, 0, stream>>>(fc1xt_w, conv_b, xtb);
    xc_convbias_kernel<<<(NB * 128 + 255) / 256, 256, 0, stream>>>(xtb, xc);
    launch_gemm_bf16(aggwb, Wct, nullptr, xc + 128, NB, 128, 6656, 6656, 384, 128, 0, 0, 8, stream);

    // ---- FG branch ----
    launch_gemm_bf16(embsb, fglint, fg_lin_b, Fbuf, NB * 13, 300, 160, 160, 320, 320, 0, 1, 1, stream);
    launch_gemm_bf16(Fbuf, wkt, nullptr, Kbuf, NB * 13, 300, 320, 320, 320, 320, 0, 1, 1, stream);
    launch_gemm_bf16(Fbuf, wvt, nullptr, Vbuf, NB * 13, 300, 320, 320, 320, 320, 0, 1, 1, stream);
    launch_gemm_bf16(Fbuf, wqt, nullptr, Qbuf, NB, 300, 320, 13 * 320, 320, 320, 0, 1, 1, stream);
    attn_ln_kernel<<<NB, 256, 0, stream>>>(Fbuf, Kbuf, Vbuf, Qbuf, ln_g, ln_b, f2row);
    launch_gemm_bf16(f2row, fgoutt, fg_out_b, xc + 256, NB, 128, 320, 320, 384, 128, 0, 0, 1, stream);

    // ---- head ----
    cvt_pad_kernel<<<((long)NB * 384 + 255) / 256, 256, 0, stream>>>(xc, xcb, NB, 384, 384);
    launch_gemm_bf16(xcb, fc1t, fc1_b, G1b, NB, 1024, 384, 384, 1024, 1024, 1, 1, 1, stream);
    launch_gemm_bf16(G1b, fc2t, fc2_b, F2, NB, 512, 1024, 1024, 512, 512, 1, 0, 1, stream);
    final_out_kernel<<<NB, 256, 0, stream>>>(F2, out_w, out_b, (float*)d_out);
}

// Round 5
// 1022.350 us; speedup vs baseline: 2.9010x; 1.2981x over previous
//
#include <hip/hip_runtime.h>
#include <hip/hip_bf16.h>
#include <math.h>

// ---------------------------------------------------------------------------
// Problem constants
// ---------------------------------------------------------------------------
#define NNODES 100000
#define NEDGES 400000
#define NB     1024
#define SEQ    1000
#define HID    300

typedef __attribute__((ext_vector_type(8))) short short8;   // 8 bf16 (4 VGPRs)
typedef __attribute__((ext_vector_type(4))) float f32x4;    // MFMA acc

__device__ __forceinline__ float bf_lo(unsigned int v) { return __uint_as_float(v << 16); }
__device__ __forceinline__ float bf_hi(unsigned int v) { return __uint_as_float(v & 0xffff0000u); }
__device__ __forceinline__ unsigned int bf_pack(float lo, float hi) {
    __hip_bfloat16 a = __float2bfloat16(lo), b = __float2bfloat16(hi);
    unsigned short ua = *(unsigned short*)&a, ub = *(unsigned short*)&b;
    return (unsigned int)ua | ((unsigned int)ub << 16);
}

// ---------------------------------------------------------------------------
// fp32 [M][K] -> bf16 [M][Kpad] (zero-padded)
// ---------------------------------------------------------------------------
__global__ void cvt_pad_kernel(const float* __restrict__ in, __hip_bfloat16* __restrict__ out,
                               int M, int K, int Kpad)
{
    long idx = (long)blockIdx.x * 256 + threadIdx.x;
    if (idx >= (long)M * Kpad) return;
    int m = idx / Kpad, k = idx % Kpad;
    out[idx] = __float2bfloat16(k < K ? in[(long)m * K + k] : 0.f);
}

// fp32 [K][N] row-major -> bf16 Bt [N][Kpad] (zero-padded)
__global__ void transpose_cvt_kernel(const float* __restrict__ in, __hip_bfloat16* __restrict__ out,
                                     int K, int N, int Kpad)
{
    long idx = (long)blockIdx.x * 256 + threadIdx.x;
    if (idx >= (long)N * Kpad) return;
    int n = idx / Kpad, k = idx % Kpad;
    out[idx] = __float2bfloat16(k < K ? in[(long)k * N + n] : 0.f);
}

// ---------------------------------------------------------------------------
// BF16 MFMA GEMM (TN): C = act(A @ Bt^T + bias)
// ---------------------------------------------------------------------------
__global__ __launch_bounds__(256) void gemm_bf16_kernel(
    const __hip_bfloat16* __restrict__ A, const __hip_bfloat16* __restrict__ Bt,
    const float* __restrict__ bias, void* __restrict__ C,
    int M, int N, int Kpad, int lda, int ldc, int Npad_out,
    int relu, int outbf, int chunk)
{
    __shared__ __align__(16) __hip_bfloat16 As[64][40];  // 32 data + 8 pad
    __shared__ __align__(16) __hip_bfloat16 Bs[64][40];
    int tid = threadIdx.x;
    int wave = tid >> 6, lane = tid & 63;
    int wm = wave >> 1, wn = wave & 1;
    int quad = lane >> 4, l16 = lane & 15;
    int row0 = blockIdx.y * 64, col0 = blockIdx.x * 64;

    int kbeg = 0, kend = Kpad;
    if (chunk > 0) { kbeg = blockIdx.z * chunk; kend = kbeg + chunk; if (kend > Kpad) kend = Kpad; }

    f32x4 acc[2][2];
    #pragma unroll
    for (int i = 0; i < 2; ++i)
        #pragma unroll
        for (int j = 0; j < 2; ++j) acc[i][j] = (f32x4){0.f, 0.f, 0.f, 0.f};

    int r = tid >> 2, cch = (tid & 3) * 8;   // stage: 64 rows x 4 chunks of 8 bf16

    for (int k0 = kbeg; k0 < kend; k0 += 32) {
        uint4 av = {0u, 0u, 0u, 0u};
        if (row0 + r < M) av = *(const uint4*)(A + (size_t)(row0 + r) * lda + k0 + cch);
        *(uint4*)(&As[r][cch]) = av;
        uint4 bv = {0u, 0u, 0u, 0u};
        if (col0 + r < N) bv = *(const uint4*)(Bt + (size_t)(col0 + r) * Kpad + k0 + cch);
        *(uint4*)(&Bs[r][cch]) = bv;
        __syncthreads();

        short8 a0 = *(const short8*)(&As[wm * 32 + l16][quad * 8]);
        short8 a1 = *(const short8*)(&As[wm * 32 + 16 + l16][quad * 8]);
        short8 b0 = *(const short8*)(&Bs[wn * 32 + l16][quad * 8]);
        short8 b1 = *(const short8*)(&Bs[wn * 32 + 16 + l16][quad * 8]);
        acc[0][0] = __builtin_amdgcn_mfma_f32_16x16x32_bf16(a0, b0, acc[0][0], 0, 0, 0);
        acc[0][1] = __builtin_amdgcn_mfma_f32_16x16x32_bf16(a0, b1, acc[0][1], 0, 0, 0);
        acc[1][0] = __builtin_amdgcn_mfma_f32_16x16x32_bf16(a1, b0, acc[1][0], 0, 0, 0);
        acc[1][1] = __builtin_amdgcn_mfma_f32_16x16x32_bf16(a1, b1, acc[1][1], 0, 0, 0);
        __syncthreads();
    }

    #pragma unroll
    for (int ti = 0; ti < 2; ++ti) {
        int rbase = row0 + wm * 32 + ti * 16 + quad * 4;
        #pragma unroll
        for (int tj = 0; tj < 2; ++tj) {
            int cc = col0 + wn * 32 + tj * 16 + l16;
            if (cc >= Npad_out) continue;
            #pragma unroll
            for (int reg = 0; reg < 4; ++reg) {
                int rr = rbase + reg;
                if (rr >= M) continue;
                float v = acc[ti][tj][reg];
                if (chunk > 0) {
                    if (cc < N) atomicAdd((float*)C + (size_t)rr * ldc + cc, v);
                } else {
                    float ov = 0.f;
                    if (cc < N) {
                        if (bias) v += bias[cc];
                        if (relu) v = fmaxf(v, 0.f);
                        ov = v;
                    }
                    if (outbf) ((__hip_bfloat16*)C)[(size_t)rr * ldc + cc] = __float2bfloat16(ov);
                    else       ((float*)C)[(size_t)rr * ldc + cc] = ov;
                }
            }
        }
    }
}

static void launch_gemm_bf16(const __hip_bfloat16* A, const __hip_bfloat16* Bt, const float* bias,
                             void* C, int M, int N, int Kpad, int lda, int ldc, int Npad_out,
                             int relu, int outbf, int splitz, hipStream_t stream)
{
    int cover = N > Npad_out ? N : Npad_out;
    int chunk = (splitz > 1) ? (Kpad / splitz) : 0;
    dim3 grid((cover + 63) / 64, (M + 63) / 64, splitz > 1 ? splitz : 1);
    gemm_bf16_kernel<<<grid, 256, 0, stream>>>(A, Bt, bias, C, M, N, Kpad, lda, ldc, Npad_out,
                                               relu, outbf, chunk);
}

// ---------------------------------------------------------------------------
// GCN: degree, norms, CSR build
// ---------------------------------------------------------------------------
__global__ void deg_kernel(const int* __restrict__ dst, int* __restrict__ deg, int E)
{
    int e = blockIdx.x * 256 + threadIdx.x;
    if (e < E) atomicAdd(&deg[dst[e]], 1);
}

__global__ void dis_kernel(const int* __restrict__ deg, float* __restrict__ dis,
                           float* __restrict__ selfc, int n)
{
    int i = blockIdx.x * 256 + threadIdx.x;
    if (i < n) {
        float d = (float)deg[i] + 1.0f;
        float r = 1.0f / sqrtf(d);
        dis[i] = r;
        selfc[i] = r * r;
    }
}

__global__ __launch_bounds__(1024) void scan_kernel(const int* __restrict__ deg,
                                                    int* __restrict__ off)
{
    __shared__ int ssum[1024];
    int tid = threadIdx.x;
    const int CH = (NNODES + 1023) / 1024;  // 98
    int start = tid * CH;
    int end = start + CH; if (end > NNODES) end = NNODES;
    int s = 0;
    for (int i = start; i < end && i < NNODES; ++i) s += deg[i];
    ssum[tid] = s;
    __syncthreads();
    for (int d = 1; d < 1024; d <<= 1) {
        int v = ssum[tid];
        int add = (tid >= d) ? ssum[tid - d] : 0;
        __syncthreads();
        ssum[tid] = v + add;
        __syncthreads();
    }
    int pre = ssum[tid] - s;
    for (int i = start; i < end && i < NNODES; ++i) { off[i] = pre; pre += deg[i]; }
    if (tid == 0) off[NNODES] = NEDGES;
}

__global__ void cur_init_kernel(const int* __restrict__ off, int* __restrict__ cur, int n)
{
    int i = blockIdx.x * 256 + threadIdx.x;
    if (i < n) cur[i] = off[i];
}

__global__ void fill_csr_kernel(const int* __restrict__ src, const int* __restrict__ dst,
                                const float* __restrict__ dis, int* __restrict__ cur,
                                int* __restrict__ csr_src, float* __restrict__ csr_w, int E)
{
    int e = blockIdx.x * 256 + threadIdx.x;
    if (e >= E) return;
    int s = src[e], d = dst[e];
    int p = atomicAdd(&cur[d], 1);
    csr_src[p] = s;
    csr_w[p] = dis[s] * dis[d];
}

// ---------------------------------------------------------------------------
// Pre-GEMM GCN aggregation: out[i] = selfc[i]*T[i] + sum_e w_e * T[src_e]
// bf16 in/out, vectorized 2 features (1 uint) per lane, <=2 chunks per row.
// half = Fpad/2 (row length in uints); nc = number of 64-uint chunks.
// ---------------------------------------------------------------------------
__global__ __launch_bounds__(256) void gcn_agg2(
    const __hip_bfloat16* __restrict__ Tin, const int* __restrict__ off,
    const int* __restrict__ csr_src, const float* __restrict__ csr_w,
    const float* __restrict__ selfc, __hip_bfloat16* __restrict__ out,
    int half, int nc)
{
    int wave = threadIdx.x >> 6, lane = threadIdx.x & 63;
    int node = blockIdx.x * 4 + wave;
    if (node >= NNODES) return;
    const unsigned int* Tp = (const unsigned int*)Tin;
    unsigned int* Op = (unsigned int*)out;
    size_t rb = (size_t)node * half;
    bool m0 = lane < half;
    bool m1 = (nc > 1) && (lane + 64 < half);
    float sc = selfc[node];
    float a0x = 0.f, a0y = 0.f, a1x = 0.f, a1y = 0.f;
    if (m0) { unsigned int v = Tp[rb + lane];      a0x = bf_lo(v) * sc; a0y = bf_hi(v) * sc; }
    if (m1) { unsigned int v = Tp[rb + lane + 64]; a1x = bf_lo(v) * sc; a1y = bf_hi(v) * sc; }
    int s0 = off[node], s1 = off[node + 1];
    for (int e = s0; e < s1; ++e) {
        size_t sb = (size_t)csr_src[e] * half;
        float w = csr_w[e];
        if (m0) { unsigned int v = Tp[sb + lane];      a0x += bf_lo(v) * w; a0y += bf_hi(v) * w; }
        if (m1) { unsigned int v = Tp[sb + lane + 64]; a1x += bf_lo(v) * w; a1y += bf_hi(v) * w; }
    }
    if (m0) Op[rb + lane]      = bf_pack(a0x, a0y);
    if (m1) Op[rb + lane + 64] = bf_pack(a1x, a1y);
}

// ---------------------------------------------------------------------------
// segment max pool (bf16 [NNODES][320] -> bf16 [NB][320]); batch sorted
// ---------------------------------------------------------------------------
__global__ __launch_bounds__(256) void pool_max_bf16(
    const __hip_bfloat16* __restrict__ H, const int* __restrict__ batch,
    __hip_bfloat16* __restrict__ g)
{
    int b = blockIdx.x;
    int lo = 0, hi = NNODES;
    while (lo < hi) { int mid = (lo + hi) >> 1; if (batch[mid] < b) lo = mid + 1; else hi = mid; }
    int s = lo;
    hi = NNODES;
    while (lo < hi) { int mid = (lo + hi) >> 1; if (batch[mid] < b + 1) lo = mid + 1; else hi = mid; }
    int e = lo;
    int tid = threadIdx.x;
    if (tid < 160) {
        const unsigned int* Hp = (const unsigned int*)H;
        float mx = 0.f, my = 0.f;   // post-relu values >= 0; pad cols are 0
        for (int i = s; i < e; ++i) {
            unsigned int v = Hp[(size_t)i * 160 + tid];
            mx = fmaxf(mx, bf_lo(v));
            my = fmaxf(my, bf_hi(v));
        }
        ((unsigned int*)g)[(size_t)b * 160 + tid] = bf_pack(mx, my);
    }
}

// ---------------------------------------------------------------------------
// Conv branch: bucketing + weight folding
// ---------------------------------------------------------------------------
__global__ void conv_transpose_kernel(const float* __restrict__ w, float* __restrict__ wt)
{
    int idx = blockIdx.x * 256 + threadIdx.x;
    if (idx >= 256000) return;
    int o = idx / 8000;
    int rem = idx - o * 8000;
    int i = rem >> 3, k = rem & 7;
    wt[i * 256 + o * 8 + k] = w[idx];
}

__global__ __launch_bounds__(256) void conv_agg_kernel(
    const float* __restrict__ cwt, const int* __restrict__ target,
    __hip_bfloat16* __restrict__ aggw)
{
    int b = blockIdx.x, tid = threadIdx.x;
    __shared__ float s[26 * 256];
    for (int i = tid; i < 26 * 256; i += 256) s[i] = 0.f;
    __syncthreads();
    const int* tb = target + b * SEQ;
    for (int i = 0; i < SEQ; ++i) {
        int a = tb[i];
        s[a * 256 + tid] += cwt[i * 256 + tid];
    }
    __syncthreads();
    for (int i = tid; i < 26 * 256; i += 256)
        aggw[(size_t)b * 6656 + i] = __float2bfloat16(s[i]);
}

__global__ __launch_bounds__(128) void conv_wc_kernel(
    const float* __restrict__ emb, const float* __restrict__ w_fc, float* __restrict__ Wc)
{
    int o = blockIdx.x;      // 0..31
    int ak = blockIdx.y;     // 0..207
    int a = ak >> 3, k = ak & 7;
    int j = threadIdx.x;
    const float* wp = w_fc + (long)(o * 121) * 128 + j;
    const float* ep = emb + a * 128 + k;
    float s = 0.f;
    #pragma unroll 11
    for (int t = 0; t < 121; ++t) s += ep[t] * wp[t * 128];
    Wc[(long)(a * 256 + o * 8 + k) * 128 + j] = s;
}

__global__ void xtb_init_kernel(const float* __restrict__ b_fc, float* __restrict__ xtb)
{
    xtb[threadIdx.x] = b_fc[threadIdx.x];
}

__global__ __launch_bounds__(128) void convb_fold_kernel(
    const float* __restrict__ w_fc, const float* __restrict__ conv_b, float* __restrict__ xtb)
{
    int o = blockIdx.x, j = threadIdx.x;
    const float* wp = w_fc + (long)(o * 121) * 128 + j;
    float s = 0.f;
    for (int t = 0; t < 121; ++t) s += wp[t * 128];
    atomicAdd(&xtb[j], s * conv_b[o]);
}

__global__ void xc_convbias_kernel(const float* __restrict__ xtb, float* __restrict__ xc)
{
    int idx = blockIdx.x * 256 + threadIdx.x;
    if (idx >= NB * 128) return;
    int b = idx >> 7, j = idx & 127;
    xc[(long)b * 384 + 128 + j] = xtb[j];
}

// ---------------------------------------------------------------------------
// FG branch: attention row 0 + LayerNorm (bf16 in, bf16 padded out)
// ---------------------------------------------------------------------------
__global__ __launch_bounds__(256) void attn_ln_kernel(
    const __hip_bfloat16* __restrict__ Fb, const __hip_bfloat16* __restrict__ Kf,
    const __hip_bfloat16* __restrict__ Vf, const __hip_bfloat16* __restrict__ q0,
    const float* __restrict__ ln_g, const float* __restrict__ ln_b,
    __hip_bfloat16* __restrict__ out)
{
    int b = blockIdx.x, tid = threadIdx.x;
    __shared__ float qs[HID];
    __shared__ float sc[13];
    __shared__ float red[256];
    __shared__ float red2[256];
    __shared__ float rowv[HID];
    __shared__ float mean_s, inv_s;

    for (int d = tid; d < HID; d += 256) qs[d] = __bfloat162float(q0[(size_t)b * 320 + d]);
    __syncthreads();
    if (tid < 208) {
        int k = tid >> 4, sub = tid & 15;
        const __hip_bfloat16* kr = Kf + ((size_t)b * 13 + k) * 320;
        float p = 0.f;
        for (int d = sub; d < HID; d += 16) p += qs[d] * __bfloat162float(kr[d]);
        red[tid] = p;
    }
    __syncthreads();
    if (tid < 208 && (tid & 15) == 0) {
        float s = 0.f;
        #pragma unroll
        for (int j = 0; j < 16; ++j) s += red[tid + j];
        sc[tid >> 4] = s * 0.0577350269189626f;  // 1/sqrt(300)
    }
    __syncthreads();
    if (tid == 0) {
        float mx = sc[0];
        for (int k = 1; k < 13; ++k) mx = fmaxf(mx, sc[k]);
        float ssum = 0.f;
        for (int k = 0; k < 13; ++k) { float e = expf(sc[k] - mx); sc[k] = e; ssum += e; }
        float inv = 1.0f / ssum;
        for (int k = 0; k < 13; ++k) sc[k] *= inv;
    }
    __syncthreads();
    for (int d = tid; d < HID; d += 256) {
        float v = __bfloat162float(Fb[((size_t)b * 13) * 320 + d]);
        #pragma unroll
        for (int k = 0; k < 13; ++k)
            v += sc[k] * __bfloat162float(Vf[((size_t)b * 13 + k) * 320 + d]);
        rowv[d] = v;
    }
    __syncthreads();
    float s1 = 0.f, s2 = 0.f;
    for (int d = tid; d < HID; d += 256) { float v = rowv[d]; s1 += v; s2 += v * v; }
    red[tid] = s1; red2[tid] = s2;
    __syncthreads();
    for (int s = 128; s > 0; s >>= 1) {
        if (tid < s) { red[tid] += red[tid + s]; red2[tid] += red2[tid + s]; }
        __syncthreads();
    }
    if (tid == 0) {
        float mean = red[0] / (float)HID;
        float var = red2[0] / (float)HID - mean * mean;
        mean_s = mean;
        inv_s = 1.0f / sqrtf(var + 1e-5f);
    }
    __syncthreads();
    for (int d = tid; d < 320; d += 256) {
        float v = 0.f;
        if (d < HID) v = (rowv[d] - mean_s) * inv_s * ln_g[d] + ln_b[d];
        out[(size_t)b * 320 + d] = __float2bfloat16(v);
    }
}

// ---------------------------------------------------------------------------
// final: out[b] = X[b,:512] . out_w + out_b   (fp32)
// ---------------------------------------------------------------------------
__global__ __launch_bounds__(256) void final_out_kernel(
    const float* __restrict__ X, const float* __restrict__ w,
    const float* __restrict__ bias, float* __restrict__ out)
{
    int b = blockIdx.x, tid = threadIdx.x;
    __shared__ float red[256];
    float p = X[(long)b * 512 + tid] * w[tid] + X[(long)b * 512 + tid + 256] * w[tid + 256];
    red[tid] = p;
    __syncthreads();
    for (int s = 128; s > 0; s >>= 1) {
        if (tid < s) red[tid] += red[tid + s];
        __syncthreads();
    }
    if (tid == 0) out[b] = red[0] + bias[0];
}

// ---------------------------------------------------------------------------
// Host launcher
// ---------------------------------------------------------------------------
extern "C" void kernel_launch(void* const* d_in, const int* in_sizes, int n_in,
                              void* d_out, int out_size, void* d_ws, size_t ws_size,
                              hipStream_t stream)
{
    const float* x        = (const float*)d_in[0];
    const int*   ei       = (const int*)d_in[1];
    const int*   batch    = (const int*)d_in[2];
    const int*   target   = (const int*)d_in[3];
    const float* embs     = (const float*)d_in[4];
    const float* W1       = (const float*)d_in[5];
    const float* b1       = (const float*)d_in[6];
    const float* W2       = (const float*)d_in[7];
    const float* b2       = (const float*)d_in[8];
    const float* W3       = (const float*)d_in[9];
    const float* b3       = (const float*)d_in[10];
    const float* fc_g1_w  = (const float*)d_in[11];
    const float* fc_g1_b  = (const float*)d_in[12];
    const float* fc_g2_w  = (const float*)d_in[13];
    const float* fc_g2_b  = (const float*)d_in[14];
    const float* emb_xt   = (const float*)d_in[15];
    const float* conv_w   = (const float*)d_in[16];
    const float* conv_b   = (const float*)d_in[17];
    const float* fc1xt_w  = (const float*)d_in[18];
    const float* fc1xt_b  = (const float*)d_in[19];
    const float* fg_lin_w = (const float*)d_in[20];
    const float* fg_lin_b = (const float*)d_in[21];
    const float* Wq       = (const float*)d_in[22];
    const float* Wk       = (const float*)d_in[23];
    const float* Wv       = (const float*)d_in[24];
    const float* ln_g     = (const float*)d_in[25];
    const float* ln_b     = (const float*)d_in[26];
    const float* fg_out_w = (const float*)d_in[27];
    const float* fg_out_b = (const float*)d_in[28];
    const float* fc1_w    = (const float*)d_in[29];
    const float* fc1_b    = (const float*)d_in[30];
    const float* fc2_w    = (const float*)d_in[31];
    const float* fc2_b    = (const float*)d_in[32];
    const float* out_w    = (const float*)d_in[33];
    const float* out_b    = (const float*)d_in[34];

    const int* src = ei;
    const int* dst = ei + NEDGES;
    typedef __hip_bfloat16 bf;

    // ---- workspace carve (256-B aligned bump allocator) ----
    char* p = (char*)d_ws;
    auto alloc = [&](size_t bytes) { char* r = p; p += (bytes + 255) & ~(size_t)255; return r; };
    bf*   xb      = (bf*)alloc((size_t)NNODES * 96 * 2);
    bf*   T       = (bf*)alloc((size_t)NNODES * 160 * 2);   // aggregated input (pre-GEMM)
    bf*   H       = (bf*)alloc((size_t)NNODES * 320 * 2);   // layer output
    int*  deg     = (int*)alloc(NNODES * 4);
    float* dis    = (float*)alloc(NNODES * 4);
    float* selfc  = (float*)alloc(NNODES * 4);
    int*  off     = (int*)alloc((NNODES + 1) * 4);
    int*  csr_src = (int*)alloc(NEDGES * 4);
    float* csr_w  = (float*)alloc(NEDGES * 4);
    bf*   w1t     = (bf*)alloc(78 * 96 * 2);
    bf*   w2t     = (bf*)alloc(156 * 96 * 2);
    bf*   w3t     = (bf*)alloc(312 * 160 * 2);
    bf*   fcg1t   = (bf*)alloc(1024 * 320 * 2);
    bf*   fcg2t   = (bf*)alloc(128 * 1024 * 2);
    bf*   fglint  = (bf*)alloc(300 * 160 * 2);
    bf*   wkt     = (bf*)alloc(300 * 320 * 2);
    bf*   wvt     = (bf*)alloc(300 * 320 * 2);
    bf*   wqt     = (bf*)alloc(300 * 320 * 2);
    bf*   fgoutt  = (bf*)alloc(128 * 320 * 2);
    bf*   fc1t    = (bf*)alloc(1024 * 384 * 2);
    bf*   fc2t    = (bf*)alloc(512 * 1024 * 2);
    bf*   g       = (bf*)alloc((size_t)NB * 320 * 2);
    bf*   G1b     = (bf*)alloc((size_t)NB * 1024 * 2);
    bf*   embsb   = (bf*)alloc((size_t)NB * 13 * 160 * 2);
    bf*   Fbuf    = (bf*)alloc((size_t)NB * 13 * 320 * 2);
    bf*   Kbuf    = (bf*)alloc((size_t)NB * 13 * 320 * 2);
    bf*   Vbuf    = (bf*)alloc((size_t)NB * 13 * 320 * 2);
    bf*   Qbuf    = (bf*)alloc((size_t)NB * 320 * 2);
    bf*   f2row   = (bf*)alloc((size_t)NB * 320 * 2);
    float* xc     = (float*)alloc((size_t)NB * 384 * 4);
    bf*   xcb     = (bf*)alloc((size_t)NB * 384 * 2);
    float* F2     = (float*)alloc((size_t)NB * 512 * 4);
    float* cwt    = (float*)alloc(256000 * 4);
    bf*   aggwb   = (bf*)alloc((size_t)NB * 6656 * 2);
    float* Wc     = (float*)alloc((size_t)6656 * 128 * 4);
    bf*   Wct     = (bf*)alloc((size_t)128 * 6656 * 2);
    float* xtb    = (float*)alloc(128 * 4);

    // ---- degree / norms / CSR ----
    hipMemsetAsync(deg, 0, NNODES * sizeof(int), stream);
    deg_kernel<<<(NEDGES + 255) / 256, 256, 0, stream>>>(dst, deg, NEDGES);
    dis_kernel<<<(NNODES + 255) / 256, 256, 0, stream>>>(deg, dis, selfc, NNODES);
    scan_kernel<<<1, 1024, 0, stream>>>(deg, off);
    cur_init_kernel<<<(NNODES + 255) / 256, 256, 0, stream>>>(off, deg, NNODES);
    fill_csr_kernel<<<(NEDGES + 255) / 256, 256, 0, stream>>>(src, dst, dis, deg, csr_src, csr_w, NEDGES);

    // ---- weight transposes / input converts ----
    auto tcvt = [&](const float* W, bf* Bt, int K, int N, int Kpad) {
        long tot = (long)N * Kpad;
        transpose_cvt_kernel<<<(tot + 255) / 256, 256, 0, stream>>>(W, Bt, K, N, Kpad);
    };
    tcvt(W1, w1t, 78, 78, 96);
    tcvt(W2, w2t, 78, 156, 96);
    tcvt(W3, w3t, 156, 312, 160);
    tcvt(fc_g1_w, fcg1t, 312, 1024, 320);
    tcvt(fc_g2_w, fcg2t, 1024, 128, 1024);
    tcvt(fg_lin_w, fglint, 133, 300, 160);
    tcvt(Wk, wkt, 300, 300, 320);
    tcvt(Wv, wvt, 300, 300, 320);
    tcvt(Wq, wqt, 300, 300, 320);
    tcvt(fg_out_w, fgoutt, 300, 128, 320);
    tcvt(fc1_w, fc1t, 384, 1024, 384);
    tcvt(fc2_w, fc2t, 1024, 512, 1024);
    cvt_pad_kernel<<<((long)NNODES * 96 + 255) / 256, 256, 0, stream>>>(x, xb, NNODES, 78, 96);
    cvt_pad_kernel<<<((long)NB * 13 * 160 + 255) / 256, 256, 0, stream>>>(embs, embsb, NB * 13, 133, 160);

    // ---- GCN layers: agg(input) -> MFMA GEMM (+bias+relu), using A(XW)=(AX)W ----
    int agrid = (NNODES + 3) / 4;
    gcn_agg2<<<agrid, 256, 0, stream>>>(xb, off, csr_src, csr_w, selfc, T, 48, 1);
    launch_gemm_bf16(T, w1t, b1, H, NNODES, 78, 96, 96, 96, 96, 1, 1, 1, stream);

    gcn_agg2<<<agrid, 256, 0, stream>>>(H, off, csr_src, csr_w, selfc, T, 48, 1);
    launch_gemm_bf16(T, w2t, b2, H, NNODES, 156, 96, 96, 160, 160, 1, 1, 1, stream);

    gcn_agg2<<<agrid, 256, 0, stream>>>(H, off, csr_src, csr_w, selfc, T, 80, 2);
    launch_gemm_bf16(T, w3t, b3, H, NNODES, 312, 160, 160, 320, 320, 1, 1, 1, stream);

    // ---- global max pool + graph MLP ----
    pool_max_bf16<<<NB, 256, 0, stream>>>(H, batch, g);
    launch_gemm_bf16(g, fcg1t, fc_g1_b, G1b, NB, 1024, 320, 320, 1024, 1024, 1, 1, 1, stream);
    launch_gemm_bf16(G1b, fcg2t, fc_g2_b, xc, NB, 128, 1024, 1024, 384, 128, 0, 0, 1, stream);

    // ---- conv branch (folded; split-K MFMA accumulates into xc cols 128..255) ----
    conv_transpose_kernel<<<(256000 + 255) / 256, 256, 0, stream>>>(conv_w, cwt);
    conv_agg_kernel<<<NB, 256, 0, stream>>>(cwt, target, aggwb);
    conv_wc_kernel<<<dim3(32, 208), 128, 0, stream>>>(emb_xt, fc1xt_w, Wc);
    transpose_cvt_kernel<<<((long)128 * 6656 + 255) / 256, 256, 0, stream>>>(Wc, Wct, 6656, 128, 6656);
    xtb_init_kernel<<<1, 128, 0, stream>>>(fc1xt_b, xtb);
    convb_fold_kernel<<<32, 128, 0, stream>>>(fc1xt_w, conv_b, xtb);
    xc_convbias_kernel<<<(NB * 128 + 255) / 256, 256, 0, stream>>>(xtb, xc);
    launch_gemm_bf16(aggwb, Wct, nullptr, xc + 128, NB, 128, 6656, 6656, 384, 128, 0, 0, 8, stream);

    // ---- FG branch ----
    launch_gemm_bf16(embsb, fglint, fg_lin_b, Fbuf, NB * 13, 300, 160, 160, 320, 320, 0, 1, 1, stream);
    launch_gemm_bf16(Fbuf, wkt, nullptr, Kbuf, NB * 13, 300, 320, 320, 320, 320, 0, 1, 1, stream);
    launch_gemm_bf16(Fbuf, wvt, nullptr, Vbuf, NB * 13, 300, 320, 320, 320, 320, 0, 1, 1, stream);
    launch_gemm_bf16(Fbuf, wqt, nullptr, Qbuf, NB, 300, 320, 13 * 320, 320, 320, 0, 1, 1, stream);
    attn_ln_kernel<<<NB, 256, 0, stream>>>(Fbuf, Kbuf, Vbuf, Qbuf, ln_g, ln_b, f2row);
    launch_gemm_bf16(f2row, fgoutt, fg_out_b, xc + 256, NB, 128, 320, 320, 384, 128, 0, 0, 1, stream);

    // ---- head ----
    cvt_pad_kernel<<<((long)NB * 384 + 255) / 256, 256, 0, stream>>>(xc, xcb, NB, 384, 384);
    launch_gemm_bf16(xcb, fc1t, fc1_b, G1b, NB, 1024, 384, 384, 1024, 1024, 1, 1, 1, stream);
    launch_gemm_bf16(G1b, fc2t, fc2_b, F2, NB, 512, 1024, 1024, 512, 512, 1, 0, 1, stream);
    final_out_kernel<<<NB, 256, 0, stream>>>(F2, out_w, out_b, (float*)d_out);
}

// Round 6
// 841.156 us; speedup vs baseline: 3.5259x; 1.2154x over previous
//
#include <hip/hip_runtime.h>
#include <hip/hip_bf16.h>
#include <math.h>

// ---------------------------------------------------------------------------
// Problem constants
// ---------------------------------------------------------------------------
#define NNODES 100000
#define NEDGES 400000
#define NB     1024
#define SEQ    1000
#define HID    300
#define NBLK1  ((NNODES + 255) / 256)   // 391

typedef __attribute__((ext_vector_type(8))) short short8;   // 8 bf16 (4 VGPRs)
typedef __attribute__((ext_vector_type(4))) float f32x4;    // MFMA acc

__device__ __forceinline__ float bf_lo(unsigned int v) { return __uint_as_float(v << 16); }
__device__ __forceinline__ float bf_hi(unsigned int v) { return __uint_as_float(v & 0xffff0000u); }
__device__ __forceinline__ unsigned int bf_pack(float lo, float hi) {
    __hip_bfloat16 a = __float2bfloat16(lo), b = __float2bfloat16(hi);
    unsigned short ua = *(unsigned short*)&a, ub = *(unsigned short*)&b;
    return (unsigned int)ua | ((unsigned int)ub << 16);
}

// ---------------------------------------------------------------------------
// fp32 [M][K] -> bf16 [M][Kpad] (zero-padded)
// ---------------------------------------------------------------------------
__global__ void cvt_pad_kernel(const float* __restrict__ in, __hip_bfloat16* __restrict__ out,
                               int M, int K, int Kpad)
{
    long idx = (long)blockIdx.x * 256 + threadIdx.x;
    if (idx >= (long)M * Kpad) return;
    int m = idx / Kpad, k = idx % Kpad;
    out[idx] = __float2bfloat16(k < K ? in[(long)m * K + k] : 0.f);
}

// fp32 [K][N] row-major -> bf16 Bt [N][Kpad] (zero-padded); single big transpose
__global__ void transpose_cvt_kernel(const float* __restrict__ in, __hip_bfloat16* __restrict__ out,
                                     int K, int N, int Kpad)
{
    long idx = (long)blockIdx.x * 256 + threadIdx.x;
    if (idx >= (long)N * Kpad) return;
    int n = idx / Kpad, k = idx % Kpad;
    out[idx] = __float2bfloat16(k < K ? in[(long)k * N + n] : 0.f);
}

// Batched weight transpose: 12 descriptors in one launch
struct TBatch {
    const float* src[12];
    __hip_bfloat16* dst[12];
    int K[12]; int N[12]; int Kpad[12];
    int bstart[13];
};

__global__ __launch_bounds__(256) void transpose_batch_kernel(TBatch tb)
{
    int blk = blockIdx.x;
    int d = 0;
    while (d < 11 && blk >= tb.bstart[d + 1]) ++d;
    long idx = (long)(blk - tb.bstart[d]) * 256 + threadIdx.x;
    long tot = (long)tb.N[d] * tb.Kpad[d];
    if (idx >= tot) return;
    int Kpad = tb.Kpad[d];
    int n = idx / Kpad, k = idx % Kpad;
    tb.dst[d][idx] = __float2bfloat16(k < tb.K[d] ? tb.src[d][(long)k * tb.N[d] + n] : 0.f);
}

// ---------------------------------------------------------------------------
// BF16 MFMA GEMM (TN): C = act(A @ Bt^T + bias)
// ---------------------------------------------------------------------------
__global__ __launch_bounds__(256) void gemm_bf16_kernel(
    const __hip_bfloat16* __restrict__ A, const __hip_bfloat16* __restrict__ Bt,
    const float* __restrict__ bias, void* __restrict__ C,
    int M, int N, int Kpad, int lda, int ldc, int Npad_out,
    int relu, int outbf, int chunk)
{
    __shared__ __align__(16) __hip_bfloat16 As[64][40];  // 32 data + 8 pad
    __shared__ __align__(16) __hip_bfloat16 Bs[64][40];
    int tid = threadIdx.x;
    int wave = tid >> 6, lane = tid & 63;
    int wm = wave >> 1, wn = wave & 1;
    int quad = lane >> 4, l16 = lane & 15;
    int row0 = blockIdx.y * 64, col0 = blockIdx.x * 64;

    int kbeg = 0, kend = Kpad;
    if (chunk > 0) { kbeg = blockIdx.z * chunk; kend = kbeg + chunk; if (kend > Kpad) kend = Kpad; }

    f32x4 acc[2][2];
    #pragma unroll
    for (int i = 0; i < 2; ++i)
        #pragma unroll
        for (int j = 0; j < 2; ++j) acc[i][j] = (f32x4){0.f, 0.f, 0.f, 0.f};

    int r = tid >> 2, cch = (tid & 3) * 8;   // stage: 64 rows x 4 chunks of 8 bf16

    for (int k0 = kbeg; k0 < kend; k0 += 32) {
        uint4 av = {0u, 0u, 0u, 0u};
        if (row0 + r < M) av = *(const uint4*)(A + (size_t)(row0 + r) * lda + k0 + cch);
        *(uint4*)(&As[r][cch]) = av;
        uint4 bv = {0u, 0u, 0u, 0u};
        if (col0 + r < N) bv = *(const uint4*)(Bt + (size_t)(col0 + r) * Kpad + k0 + cch);
        *(uint4*)(&Bs[r][cch]) = bv;
        __syncthreads();

        short8 a0 = *(const short8*)(&As[wm * 32 + l16][quad * 8]);
        short8 a1 = *(const short8*)(&As[wm * 32 + 16 + l16][quad * 8]);
        short8 b0 = *(const short8*)(&Bs[wn * 32 + l16][quad * 8]);
        short8 b1 = *(const short8*)(&Bs[wn * 32 + 16 + l16][quad * 8]);
        acc[0][0] = __builtin_amdgcn_mfma_f32_16x16x32_bf16(a0, b0, acc[0][0], 0, 0, 0);
        acc[0][1] = __builtin_amdgcn_mfma_f32_16x16x32_bf16(a0, b1, acc[0][1], 0, 0, 0);
        acc[1][0] = __builtin_amdgcn_mfma_f32_16x16x32_bf16(a1, b0, acc[1][0], 0, 0, 0);
        acc[1][1] = __builtin_amdgcn_mfma_f32_16x16x32_bf16(a1, b1, acc[1][1], 0, 0, 0);
        __syncthreads();
    }

    #pragma unroll
    for (int ti = 0; ti < 2; ++ti) {
        int rbase = row0 + wm * 32 + ti * 16 + quad * 4;
        #pragma unroll
        for (int tj = 0; tj < 2; ++tj) {
            int cc = col0 + wn * 32 + tj * 16 + l16;
            if (cc >= Npad_out) continue;
            #pragma unroll
            for (int reg = 0; reg < 4; ++reg) {
                int rr = rbase + reg;
                if (rr >= M) continue;
                float v = acc[ti][tj][reg];
                if (chunk > 0) {
                    if (cc < N) atomicAdd((float*)C + (size_t)rr * ldc + cc, v);
                } else {
                    float ov = 0.f;
                    if (cc < N) {
                        if (bias) v += bias[cc];
                        if (relu) v = fmaxf(v, 0.f);
                        ov = v;
                    }
                    if (outbf) ((__hip_bfloat16*)C)[(size_t)rr * ldc + cc] = __float2bfloat16(ov);
                    else       ((float*)C)[(size_t)rr * ldc + cc] = ov;
                }
            }
        }
    }
}

static void launch_gemm_bf16(const __hip_bfloat16* A, const __hip_bfloat16* Bt, const float* bias,
                             void* C, int M, int N, int Kpad, int lda, int ldc, int Npad_out,
                             int relu, int outbf, int splitz, hipStream_t stream)
{
    int cover = N > Npad_out ? N : Npad_out;
    int chunk = (splitz > 1) ? (Kpad / splitz) : 0;
    dim3 grid((cover + 63) / 64, (M + 63) / 64, splitz > 1 ? splitz : 1);
    gemm_bf16_kernel<<<grid, 256, 0, stream>>>(A, Bt, bias, C, M, N, Kpad, lda, ldc, Npad_out,
                                               relu, outbf, chunk);
}

// ---------------------------------------------------------------------------
// GCN: degree, norms, multi-block scan, CSR build
// ---------------------------------------------------------------------------
__global__ void deg_kernel(const int* __restrict__ dst, int* __restrict__ deg, int E)
{
    int e = blockIdx.x * 256 + threadIdx.x;
    if (e < E) atomicAdd(&deg[dst[e]], 1);
}

__global__ void dis_kernel(const int* __restrict__ deg, float* __restrict__ dis,
                           float* __restrict__ selfc, int n)
{
    int i = blockIdx.x * 256 + threadIdx.x;
    if (i < n) {
        float d = (float)deg[i] + 1.0f;
        float r = 1.0f / sqrtf(d);
        dis[i] = r;
        selfc[i] = r * r;
    }
}

// phase 1: per-block exclusive scan of 256 degrees; block total -> bsum
__global__ __launch_bounds__(256) void scan_p1(const int* __restrict__ deg,
                                               int* __restrict__ off, int* __restrict__ bsum)
{
    __shared__ int s[256];
    int tid = threadIdx.x;
    int i = blockIdx.x * 256 + tid;
    int v = (i < NNODES) ? deg[i] : 0;
    s[tid] = v;
    __syncthreads();
    #pragma unroll
    for (int d = 1; d < 256; d <<= 1) {
        int t = (tid >= d) ? s[tid - d] : 0;
        __syncthreads();
        s[tid] += t;
        __syncthreads();
    }
    if (i < NNODES) off[i] = s[tid] - v;           // exclusive within block
    if (tid == 255) bsum[blockIdx.x] = s[255];     // block total
}

// phase 2: single-block exclusive scan of the 391 block sums
__global__ __launch_bounds__(512) void scan_p2(int* __restrict__ bsum)
{
    __shared__ int s[512];
    int tid = threadIdx.x;
    int v = (tid < NBLK1) ? bsum[tid] : 0;
    s[tid] = v;
    __syncthreads();
    #pragma unroll
    for (int d = 1; d < 512; d <<= 1) {
        int t = (tid >= d) ? s[tid - d] : 0;
        __syncthreads();
        s[tid] += t;
        __syncthreads();
    }
    if (tid < NBLK1) bsum[tid] = s[tid] - v;       // exclusive
}

// phase 3: add block offsets; also init CSR cursor (cur) and off[NNODES]
__global__ __launch_bounds__(256) void scan_p3(int* __restrict__ off, const int* __restrict__ bsum,
                                               int* __restrict__ cur)
{
    int i = blockIdx.x * 256 + threadIdx.x;
    if (i < NNODES) {
        int v = off[i] + bsum[blockIdx.x];
        off[i] = v;
        cur[i] = v;
    }
    if (i == NNODES) off[NNODES] = NEDGES;
}

__global__ void fill_csr_kernel(const int* __restrict__ src, const int* __restrict__ dst,
                                const float* __restrict__ dis, int* __restrict__ cur,
                                int* __restrict__ csr_src, float* __restrict__ csr_w, int E)
{
    int e = blockIdx.x * 256 + threadIdx.x;
    if (e >= E) return;
    int s = src[e], d = dst[e];
    int p = atomicAdd(&cur[d], 1);
    csr_src[p] = s;
    csr_w[p] = dis[s] * dis[d];
}

// ---------------------------------------------------------------------------
// Pre-GEMM GCN aggregation: out[i] = selfc[i]*T[i] + sum_e w_e * T[src_e]
// ---------------------------------------------------------------------------
__global__ __launch_bounds__(256) void gcn_agg2(
    const __hip_bfloat16* __restrict__ Tin, const int* __restrict__ off,
    const int* __restrict__ csr_src, const float* __restrict__ csr_w,
    const float* __restrict__ selfc, __hip_bfloat16* __restrict__ out,
    int half, int nc)
{
    int wave = threadIdx.x >> 6, lane = threadIdx.x & 63;
    int node = blockIdx.x * 4 + wave;
    if (node >= NNODES) return;
    const unsigned int* Tp = (const unsigned int*)Tin;
    unsigned int* Op = (unsigned int*)out;
    size_t rb = (size_t)node * half;
    bool m0 = lane < half;
    bool m1 = (nc > 1) && (lane + 64 < half);
    float sc = selfc[node];
    float a0x = 0.f, a0y = 0.f, a1x = 0.f, a1y = 0.f;
    if (m0) { unsigned int v = Tp[rb + lane];      a0x = bf_lo(v) * sc; a0y = bf_hi(v) * sc; }
    if (m1) { unsigned int v = Tp[rb + lane + 64]; a1x = bf_lo(v) * sc; a1y = bf_hi(v) * sc; }
    int s0 = off[node], s1 = off[node + 1];
    for (int e = s0; e < s1; ++e) {
        size_t sb = (size_t)csr_src[e] * half;
        float w = csr_w[e];
        if (m0) { unsigned int v = Tp[sb + lane];      a0x += bf_lo(v) * w; a0y += bf_hi(v) * w; }
        if (m1) { unsigned int v = Tp[sb + lane + 64]; a1x += bf_lo(v) * w; a1y += bf_hi(v) * w; }
    }
    if (m0) Op[rb + lane]      = bf_pack(a0x, a0y);
    if (m1) Op[rb + lane + 64] = bf_pack(a1x, a1y);
}

// ---------------------------------------------------------------------------
// segment max pool (bf16 [NNODES][320] -> bf16 [NB][320]); batch sorted
// ---------------------------------------------------------------------------
__global__ __launch_bounds__(256) void pool_max_bf16(
    const __hip_bfloat16* __restrict__ H, const int* __restrict__ batch,
    __hip_bfloat16* __restrict__ g)
{
    int b = blockIdx.x;
    int lo = 0, hi = NNODES;
    while (lo < hi) { int mid = (lo + hi) >> 1; if (batch[mid] < b) lo = mid + 1; else hi = mid; }
    int s = lo;
    hi = NNODES;
    while (lo < hi) { int mid = (lo + hi) >> 1; if (batch[mid] < b + 1) lo = mid + 1; else hi = mid; }
    int e = lo;
    int tid = threadIdx.x;
    if (tid < 160) {
        const unsigned int* Hp = (const unsigned int*)H;
        float mx = 0.f, my = 0.f;
        for (int i = s; i < e; ++i) {
            unsigned int v = Hp[(size_t)i * 160 + tid];
            mx = fmaxf(mx, bf_lo(v));
            my = fmaxf(my, bf_hi(v));
        }
        ((unsigned int*)g)[(size_t)b * 160 + tid] = bf_pack(mx, my);
    }
}

// ---------------------------------------------------------------------------
// Conv branch: bucketing + weight folding
// ---------------------------------------------------------------------------
__global__ void conv_transpose_kernel(const float* __restrict__ w, float* __restrict__ wt)
{
    int idx = blockIdx.x * 256 + threadIdx.x;
    if (idx >= 256000) return;
    int o = idx / 8000;
    int rem = idx - o * 8000;
    int i = rem >> 3, k = rem & 7;
    wt[i * 256 + o * 8 + k] = w[idx];
}

__global__ __launch_bounds__(256) void conv_agg_kernel(
    const float* __restrict__ cwt, const int* __restrict__ target,
    __hip_bfloat16* __restrict__ aggw)
{
    int b = blockIdx.x, tid = threadIdx.x;
    __shared__ float s[26 * 256];
    for (int i = tid; i < 26 * 256; i += 256) s[i] = 0.f;
    __syncthreads();
    const int* tb = target + b * SEQ;
    for (int i = 0; i < SEQ; ++i) {
        int a = tb[i];
        s[a * 256 + tid] += cwt[i * 256 + tid];
    }
    __syncthreads();
    for (int i = tid; i < 26 * 256; i += 256)
        aggw[(size_t)b * 6656 + i] = __float2bfloat16(s[i]);
}

__global__ __launch_bounds__(128) void conv_wc_kernel(
    const float* __restrict__ emb, const float* __restrict__ w_fc, float* __restrict__ Wc)
{
    int o = blockIdx.x;      // 0..31
    int ak = blockIdx.y;     // 0..207
    int a = ak >> 3, k = ak & 7;
    int j = threadIdx.x;
    const float* wp = w_fc + (long)(o * 121) * 128 + j;
    const float* ep = emb + a * 128 + k;
    float s = 0.f;
    #pragma unroll 11
    for (int t = 0; t < 121; ++t) s += ep[t] * wp[t * 128];
    Wc[(long)(a * 256 + o * 8 + k) * 128 + j] = s;
}

__global__ void xtb_init_kernel(const float* __restrict__ b_fc, float* __restrict__ xtb)
{
    xtb[threadIdx.x] = b_fc[threadIdx.x];
}

__global__ __launch_bounds__(128) void convb_fold_kernel(
    const float* __restrict__ w_fc, const float* __restrict__ conv_b, float* __restrict__ xtb)
{
    int o = blockIdx.x, j = threadIdx.x;
    const float* wp = w_fc + (long)(o * 121) * 128 + j;
    float s = 0.f;
    for (int t = 0; t < 121; ++t) s += wp[t * 128];
    atomicAdd(&xtb[j], s * conv_b[o]);
}

__global__ void xc_convbias_kernel(const float* __restrict__ xtb, float* __restrict__ xc)
{
    int idx = blockIdx.x * 256 + threadIdx.x;
    if (idx >= NB * 128) return;
    int b = idx >> 7, j = idx & 127;
    xc[(long)b * 384 + 128 + j] = xtb[j];
}

// ---------------------------------------------------------------------------
// FG branch: attention row 0 + LayerNorm (bf16 in, bf16 padded out)
// ---------------------------------------------------------------------------
__global__ __launch_bounds__(256) void attn_ln_kernel(
    const __hip_bfloat16* __restrict__ Fb, const __hip_bfloat16* __restrict__ Kf,
    const __hip_bfloat16* __restrict__ Vf, const __hip_bfloat16* __restrict__ q0,
    const float* __restrict__ ln_g, const float* __restrict__ ln_b,
    __hip_bfloat16* __restrict__ out)
{
    int b = blockIdx.x, tid = threadIdx.x;
    __shared__ float qs[HID];
    __shared__ float sc[13];
    __shared__ float red[256];
    __shared__ float red2[256];
    __shared__ float rowv[HID];
    __shared__ float mean_s, inv_s;

    for (int d = tid; d < HID; d += 256) qs[d] = __bfloat162float(q0[(size_t)b * 320 + d]);
    __syncthreads();
    if (tid < 208) {
        int k = tid >> 4, sub = tid & 15;
        const __hip_bfloat16* kr = Kf + ((size_t)b * 13 + k) * 320;
        float p = 0.f;
        for (int d = sub; d < HID; d += 16) p += qs[d] * __bfloat162float(kr[d]);
        red[tid] = p;
    }
    __syncthreads();
    if (tid < 208 && (tid & 15) == 0) {
        float s = 0.f;
        #pragma unroll
        for (int j = 0; j < 16; ++j) s += red[tid + j];
        sc[tid >> 4] = s * 0.0577350269189626f;  // 1/sqrt(300)
    }
    __syncthreads();
    if (tid == 0) {
        float mx = sc[0];
        for (int k = 1; k < 13; ++k) mx = fmaxf(mx, sc[k]);
        float ssum = 0.f;
        for (int k = 0; k < 13; ++k) { float e = expf(sc[k] - mx); sc[k] = e; ssum += e; }
        float inv = 1.0f / ssum;
        for (int k = 0; k < 13; ++k) sc[k] *= inv;
    }
    __syncthreads();
    for (int d = tid; d < HID; d += 256) {
        float v = __bfloat162float(Fb[((size_t)b * 13) * 320 + d]);
        #pragma unroll
        for (int k = 0; k < 13; ++k)
            v += sc[k] * __bfloat162float(Vf[((size_t)b * 13 + k) * 320 + d]);
        rowv[d] = v;
    }
    __syncthreads();
    float s1 = 0.f, s2 = 0.f;
    for (int d = tid; d < HID; d += 256) { float v = rowv[d]; s1 += v; s2 += v * v; }
    red[tid] = s1; red2[tid] = s2;
    __syncthreads();
    for (int s = 128; s > 0; s >>= 1) {
        if (tid < s) { red[tid] += red[tid + s]; red2[tid] += red2[tid + s]; }
        __syncthreads();
    }
    if (tid == 0) {
        float mean = red[0] / (float)HID;
        float var = red2[0] / (float)HID - mean * mean;
        mean_s = mean;
        inv_s = 1.0f / sqrtf(var + 1e-5f);
    }
    __syncthreads();
    for (int d = tid; d < 320; d += 256) {
        float v = 0.f;
        if (d < HID) v = (rowv[d] - mean_s) * inv_s * ln_g[d] + ln_b[d];
        out[(size_t)b * 320 + d] = __float2bfloat16(v);
    }
}

// ---------------------------------------------------------------------------
// final: out[b] = X[b,:512] . out_w + out_b   (fp32)
// ---------------------------------------------------------------------------
__global__ __launch_bounds__(256) void final_out_kernel(
    const float* __restrict__ X, const float* __restrict__ w,
    const float* __restrict__ bias, float* __restrict__ out)
{
    int b = blockIdx.x, tid = threadIdx.x;
    __shared__ float red[256];
    float p = X[(long)b * 512 + tid] * w[tid] + X[(long)b * 512 + tid + 256] * w[tid + 256];
    red[tid] = p;
    __syncthreads();
    for (int s = 128; s > 0; s >>= 1) {
        if (tid < s) red[tid] += red[tid + s];
        __syncthreads();
    }
    if (tid == 0) out[b] = red[0] + bias[0];
}

// ---------------------------------------------------------------------------
// Host launcher
// ---------------------------------------------------------------------------
extern "C" void kernel_launch(void* const* d_in, const int* in_sizes, int n_in,
                              void* d_out, int out_size, void* d_ws, size_t ws_size,
                              hipStream_t stream)
{
    const float* x        = (const float*)d_in[0];
    const int*   ei       = (const int*)d_in[1];
    const int*   batch    = (const int*)d_in[2];
    const int*   target   = (const int*)d_in[3];
    const float* embs     = (const float*)d_in[4];
    const float* W1       = (const float*)d_in[5];
    const float* b1       = (const float*)d_in[6];
    const float* W2       = (const float*)d_in[7];
    const float* b2       = (const float*)d_in[8];
    const float* W3       = (const float*)d_in[9];
    const float* b3       = (const float*)d_in[10];
    const float* fc_g1_w  = (const float*)d_in[11];
    const float* fc_g1_b  = (const float*)d_in[12];
    const float* fc_g2_w  = (const float*)d_in[13];
    const float* fc_g2_b  = (const float*)d_in[14];
    const float* emb_xt   = (const float*)d_in[15];
    const float* conv_w   = (const float*)d_in[16];
    const float* conv_b   = (const float*)d_in[17];
    const float* fc1xt_w  = (const float*)d_in[18];
    const float* fc1xt_b  = (const float*)d_in[19];
    const float* fg_lin_w = (const float*)d_in[20];
    const float* fg_lin_b = (const float*)d_in[21];
    const float* Wq       = (const float*)d_in[22];
    const float* Wk       = (const float*)d_in[23];
    const float* Wv       = (const float*)d_in[24];
    const float* ln_g     = (const float*)d_in[25];
    const float* ln_b     = (const float*)d_in[26];
    const float* fg_out_w = (const float*)d_in[27];
    const float* fg_out_b = (const float*)d_in[28];
    const float* fc1_w    = (const float*)d_in[29];
    const float* fc1_b    = (const float*)d_in[30];
    const float* fc2_w    = (const float*)d_in[31];
    const float* fc2_b    = (const float*)d_in[32];
    const float* out_w    = (const float*)d_in[33];
    const float* out_b    = (const float*)d_in[34];

    const int* src = ei;
    const int* dst = ei + NEDGES;
    typedef __hip_bfloat16 bf;

    // ---- workspace carve (256-B aligned bump allocator) ----
    char* p = (char*)d_ws;
    auto alloc = [&](size_t bytes) { char* r = p; p += (bytes + 255) & ~(size_t)255; return r; };
    bf*   xb      = (bf*)alloc((size_t)NNODES * 96 * 2);
    bf*   T       = (bf*)alloc((size_t)NNODES * 160 * 2);   // aggregated input (pre-GEMM)
    bf*   H       = (bf*)alloc((size_t)NNODES * 320 * 2);   // layer output
    int*  deg     = (int*)alloc(NNODES * 4);                // reused as CSR cursor
    float* dis    = (float*)alloc(NNODES * 4);
    float* selfc  = (float*)alloc(NNODES * 4);
    int*  off     = (int*)alloc((NNODES + 1) * 4);
    int*  bsum    = (int*)alloc(512 * 4);
    int*  csr_src = (int*)alloc(NEDGES * 4);
    float* csr_w  = (float*)alloc(NEDGES * 4);
    bf*   w1t     = (bf*)alloc(78 * 96 * 2);
    bf*   w2t     = (bf*)alloc(156 * 96 * 2);
    bf*   w3t     = (bf*)alloc(312 * 160 * 2);
    bf*   fcg1t   = (bf*)alloc(1024 * 320 * 2);
    bf*   fcg2t   = (bf*)alloc(128 * 1024 * 2);
    bf*   fglint  = (bf*)alloc(300 * 160 * 2);
    bf*   wkt     = (bf*)alloc(300 * 320 * 2);
    bf*   wvt     = (bf*)alloc(300 * 320 * 2);
    bf*   wqt     = (bf*)alloc(300 * 320 * 2);
    bf*   fgoutt  = (bf*)alloc(128 * 320 * 2);
    bf*   fc1t    = (bf*)alloc(1024 * 384 * 2);
    bf*   fc2t    = (bf*)alloc(512 * 1024 * 2);
    bf*   g       = (bf*)alloc((size_t)NB * 320 * 2);
    bf*   G1b     = (bf*)alloc((size_t)NB * 1024 * 2);
    bf*   embsb   = (bf*)alloc((size_t)NB * 13 * 160 * 2);
    bf*   Fbuf    = (bf*)alloc((size_t)NB * 13 * 320 * 2);
    bf*   Kbuf    = (bf*)alloc((size_t)NB * 13 * 320 * 2);
    bf*   Vbuf    = (bf*)alloc((size_t)NB * 13 * 320 * 2);
    bf*   Qbuf    = (bf*)alloc((size_t)NB * 320 * 2);
    bf*   f2row   = (bf*)alloc((size_t)NB * 320 * 2);
    float* xc     = (float*)alloc((size_t)NB * 384 * 4);
    bf*   xcb     = (bf*)alloc((size_t)NB * 384 * 2);
    float* F2     = (float*)alloc((size_t)NB * 512 * 4);
    float* cwt    = (float*)alloc(256000 * 4);
    bf*   aggwb   = (bf*)alloc((size_t)NB * 6656 * 2);
    float* Wc     = (float*)alloc((size_t)6656 * 128 * 4);
    bf*   Wct     = (bf*)alloc((size_t)128 * 6656 * 2);
    float* xtb    = (float*)alloc(128 * 4);

    // ---- degree / norms / CSR (multi-block scan) ----
    hipMemsetAsync(deg, 0, NNODES * sizeof(int), stream);
    deg_kernel<<<(NEDGES + 255) / 256, 256, 0, stream>>>(dst, deg, NEDGES);
    dis_kernel<<<(NNODES + 255) / 256, 256, 0, stream>>>(deg, dis, selfc, NNODES);
    scan_p1<<<NBLK1, 256, 0, stream>>>(deg, off, bsum);
    scan_p2<<<1, 512, 0, stream>>>(bsum);
    scan_p3<<<NBLK1, 256, 0, stream>>>(off, bsum, deg);   // deg becomes cursor
    fill_csr_kernel<<<(NEDGES + 255) / 256, 256, 0, stream>>>(src, dst, dis, deg, csr_src, csr_w, NEDGES);

    // ---- weight transposes (one batched launch) + input converts ----
    {
        TBatch tb;
        const float* srcs[12] = {W1, W2, W3, fc_g1_w, fc_g2_w, fg_lin_w, Wk, Wv, Wq, fg_out_w, fc1_w, fc2_w};
        bf* dsts[12]          = {w1t, w2t, w3t, fcg1t, fcg2t, fglint, wkt, wvt, wqt, fgoutt, fc1t, fc2t};
        int Ks[12]    = {78, 78, 156, 312, 1024, 133, 300, 300, 300, 300, 384, 1024};
        int Ns[12]    = {78, 156, 312, 1024, 128, 300, 300, 300, 300, 128, 1024, 512};
        int Kpads[12] = {96, 96, 160, 320, 1024, 160, 320, 320, 320, 320, 384, 1024};
        int bs = 0;
        for (int i = 0; i < 12; ++i) {
            tb.src[i] = srcs[i]; tb.dst[i] = dsts[i];
            tb.K[i] = Ks[i]; tb.N[i] = Ns[i]; tb.Kpad[i] = Kpads[i];
            tb.bstart[i] = bs;
            bs += (int)(((long)Ns[i] * Kpads[i] + 255) / 256);
        }
        tb.bstart[12] = bs;
        transpose_batch_kernel<<<bs, 256, 0, stream>>>(tb);
    }
    cvt_pad_kernel<<<((long)NNODES * 96 + 255) / 256, 256, 0, stream>>>(x, xb, NNODES, 78, 96);
    cvt_pad_kernel<<<((long)NB * 13 * 160 + 255) / 256, 256, 0, stream>>>(embs, embsb, NB * 13, 133, 160);

    // ---- GCN layers: agg(input) -> MFMA GEMM (+bias+relu), using A(XW)=(AX)W ----
    int agrid = (NNODES + 3) / 4;
    gcn_agg2<<<agrid, 256, 0, stream>>>(xb, off, csr_src, csr_w, selfc, T, 48, 1);
    launch_gemm_bf16(T, w1t, b1, H, NNODES, 78, 96, 96, 96, 96, 1, 1, 1, stream);

    gcn_agg2<<<agrid, 256, 0, stream>>>(H, off, csr_src, csr_w, selfc, T, 48, 1);
    launch_gemm_bf16(T, w2t, b2, H, NNODES, 156, 96, 96, 160, 160, 1, 1, 1, stream);

    gcn_agg2<<<agrid, 256, 0, stream>>>(H, off, csr_src, csr_w, selfc, T, 80, 2);
    launch_gemm_bf16(T, w3t, b3, H, NNODES, 312, 160, 160, 320, 320, 1, 1, 1, stream);

    // ---- global max pool + graph MLP ----
    pool_max_bf16<<<NB, 256, 0, stream>>>(H, batch, g);
    launch_gemm_bf16(g, fcg1t, fc_g1_b, G1b, NB, 1024, 320, 320, 1024, 1024, 1, 1, 1, stream);
    launch_gemm_bf16(G1b, fcg2t, fc_g2_b, xc, NB, 128, 1024, 1024, 384, 128, 0, 0, 1, stream);

    // ---- conv branch (folded; split-K MFMA accumulates into xc cols 128..255) ----
    conv_transpose_kernel<<<(256000 + 255) / 256, 256, 0, stream>>>(conv_w, cwt);
    conv_agg_kernel<<<NB, 256, 0, stream>>>(cwt, target, aggwb);
    conv_wc_kernel<<<dim3(32, 208), 128, 0, stream>>>(emb_xt, fc1xt_w, Wc);
    transpose_cvt_kernel<<<((long)128 * 6656 + 255) / 256, 256, 0, stream>>>(Wc, Wct, 6656, 128, 6656);
    xtb_init_kernel<<<1, 128, 0, stream>>>(fc1xt_b, xtb);
    convb_fold_kernel<<<32, 128, 0, stream>>>(fc1xt_w, conv_b, xtb);
    xc_convbias_kernel<<<(NB * 128 + 255) / 256, 256, 0, stream>>>(xtb, xc);
    launch_gemm_bf16(aggwb, Wct, nullptr, xc + 128, NB, 128, 6656, 6656, 384, 128, 0, 0, 8, stream);

    // ---- FG branch ----
    launch_gemm_bf16(embsb, fglint, fg_lin_b, Fbuf, NB * 13, 300, 160, 160, 320, 320, 0, 1, 1, stream);
    launch_gemm_bf16(Fbuf, wkt, nullptr, Kbuf, NB * 13, 300, 320, 320, 320, 320, 0, 1, 1, stream);
    launch_gemm_bf16(Fbuf, wvt, nullptr, Vbuf, NB * 13, 300, 320, 320, 320, 320, 0, 1, 1, stream);
    launch_gemm_bf16(Fbuf, wqt, nullptr, Qbuf, NB, 300, 320, 13 * 320, 320, 320, 0, 1, 1, stream);
    attn_ln_kernel<<<NB, 256, 0, stream>>>(Fbuf, Kbuf, Vbuf, Qbuf, ln_g, ln_b, f2row);
    launch_gemm_bf16(f2row, fgoutt, fg_out_b, xc + 256, NB, 128, 320, 320, 384, 128, 0, 0, 1, stream);

    // ---- head ----
    cvt_pad_kernel<<<((long)NB * 384 + 255) / 256, 256, 0, stream>>>(xc, xcb, NB, 384, 384);
    launch_gemm_bf16(xcb, fc1t, fc1_b, G1b, NB, 1024, 384, 384, 1024, 1024, 1, 1, 1, stream);
    launch_gemm_bf16(G1b, fc2t, fc2_b, F2, NB, 512, 1024, 1024, 512, 512, 1, 0, 1, stream);
    final_out_kernel<<<NB, 256, 0, stream>>>(F2, out_w, out_b, (float*)d_out);
}